// Round 11
// baseline (429.351 us; speedup 1.0000x reference)
//
#include <hip/hip_runtime.h>
#include <hip/hip_bf16.h>

// ---------------- problem constants ----------------
#define B_N 2
#define L_N 8192
#define ROWS 16384                // B_N * L_N
#define CHUNK 64
#define NCHUNK 128                // L_N / CHUNK
#define GRP 16                    // chunks per combine group
#define NGRP 8                    // NCHUNK / GRP
#define NPAD 1152                 // input-proj N padded: 2 x 544 + pad to 9*128

typedef __bf16 bf16x8 __attribute__((ext_vector_type(8)));
typedef float f32x4 __attribute__((ext_vector_type(4)));

// fast silu: 1-ulp rcp instead of IEEE divide
__device__ __forceinline__ float siluf(float v) {
  return v * __builtin_amdgcn_rcpf(1.f + __expf(-v));
}
__device__ __forceinline__ float softplusf_(float v) {
  return fmaxf(v, 0.f) + log1pf(__expf(-fabsf(v)));
}
// native bf16 convert (gfx950 HW cvt, RNE)
__device__ __forceinline__ unsigned short f2bf(float v) {
  union { __bf16 b; unsigned short u; } x;
  x.b = (__bf16)v;
  return x.u;
}
__device__ __forceinline__ float bf2f(unsigned short u) {
  union { unsigned u; float f; } x; x.u = ((unsigned)u) << 16;
  return x.f;
}

// async global->LDS, 16B per lane, LDS dest = wave-uniform base + lane*16
__device__ __forceinline__ void gload_lds16(const unsigned short* g, unsigned short* l) {
  __builtin_amdgcn_global_load_lds(
      (const __attribute__((address_space(1))) unsigned int*)g,
      (__attribute__((address_space(3))) unsigned int*)l, 16, 0, 0);
}

struct P4 { const float* p[4]; };
struct ScanConsts {
  const float* dt_bias[4];
  const float* A_log[4];
  const float* D[4];
};

// ---------------- merged prep + dtfix ----------------
// blocks [0,1024): dtfix (mat = bid>>9, rowblock = bid&511) — exact fp32 dt dot with LDS
//   staging, writes dtv/dA and xbf (bf16 cvt of x).
// blocks [1024,3328): Wt_in; [3328,4352): Wt_dirs; [4352,5376): Wt_fin; [5376,5440): inv
__global__ __launch_bounds__(256) void k_prep(
    const float* __restrict__ xH, const float* __restrict__ xV,
    const float* __restrict__ WH, const float* __restrict__ WV,
    P4 ws, const float* __restrict__ W_out, const int* __restrict__ v2h, ScanConsts sc,
    unsigned short* __restrict__ xbf, float* __restrict__ dtv_arr, float* __restrict__ dA_arr,
    unsigned short* __restrict__ Wt_in, unsigned short* __restrict__ Wt_dirs,
    unsigned short* __restrict__ Wt_fin, int* __restrict__ inv) {
  __shared__ float xs[32][257];
  __shared__ float Wsm[8][260];
  int bid = blockIdx.x;
  int tid = threadIdx.x;
  if (bid < 1024) {
    const int mat = bid >> 9;
    const float* x = mat ? xV : xH;
    const float* W = mat ? WV : WH;
    const int r0 = (bid & 511) * 32;
    for (int i = tid; i < 2048; i += 256) {
      int c = i >> 8, k = i & 255;            // c = sl*4+h
      int sl = c >> 2, h = c & 3;
      Wsm[c][k] = W[(long)k * 1064 + sl * 532 + 528 + h];
    }
    for (int i = tid; i < 32 * 64; i += 256) {
      int rl = i >> 6, kq = (i & 63) * 4;
      float4 v = *(const float4*)(x + (long)(r0 + rl) * 256 + kq);
      xs[rl][kq + 0] = v.x; xs[rl][kq + 1] = v.y; xs[rl][kq + 2] = v.z; xs[rl][kq + 3] = v.w;
    }
    __syncthreads();
    for (int i = tid; i < 32 * 64; i += 256) {
      int rl = i >> 6, kq = (i & 63) * 4;
      ushort4 o;
      o.x = f2bf(xs[rl][kq + 0]);
      o.y = f2bf(xs[rl][kq + 1]);
      o.z = f2bf(xs[rl][kq + 2]);
      o.w = f2bf(xs[rl][kq + 3]);
      *(ushort4*)(xbf + (size_t)mat * ROWS * 256 + (long)(r0 + rl) * 256 + kq) = o;
    }
    const int rl = tid >> 3, c = tid & 7;
    float s = 0.f;
    #pragma unroll 8
    for (int k = 0; k < 256; ++k) s = fmaf(xs[rl][k], Wsm[c][k], s);
    const int sl = c >> 2, h = c & 3;
    const int dir = mat * 2 + sl;
    float dtv = softplusf_(s + sc.dt_bias[dir][h]);
    float dAv = __expf(dtv * (-__expf(sc.A_log[dir][h])));
    long o = ((long)dir * 4 + h) * ROWS + (r0 + rl);
    dtv_arr[o] = dtv;
    dA_arr[o] = dAv;
  } else if (bid < 3328) {
    int i = (bid - 1024) * 256 + tid;         // 2*1152*256
    int z = i / (NPAD * 256);
    int rem = i - z * (NPAD * 256);
    int n = rem >> 8, k = rem & 255;
    const float* W = z ? WV : WH;
    int sl = n >= 544;
    int cc = n - (sl ? 544 : 0);
    float v = (cc < 532) ? W[(long)k * 1064 + sl * 532 + cc] : 0.f;
    Wt_in[i] = f2bf(v);
  } else if (bid < 4352) {
    int i = (bid - 3328) * 256 + tid;         // 4*65536
    int d = i >> 16;
    int rem = i & 65535;
    int n = rem >> 8, k = rem & 255;
    Wt_dirs[i] = f2bf(ws.p[d][(long)k * 256 + n]);
  } else if (bid < 5376) {
    int i = (bid - 4352) * 256 + tid;         // 256*1024, i = n*1024+k
    int n = i >> 10, k = i & 1023;
    Wt_fin[i] = f2bf(W_out[(long)k * 256 + n]);
  } else {
    int m = (bid - 5376) * 256 + tid;
    if (m < ROWS) {
      int b = m >> 13;
      inv[b * L_N + v2h[m]] = m;              // inv[h-row] = v-row
    }
  }
}

// ---------------- bf16 MFMA GEMM (128x128 tile, BK=32, counted-vmcnt ring-3) ----------------
struct EpiIn {
  unsigned short* zraw;   // [4][ROWS*256] raw z (silu applied in scans)
  unsigned short* xraw;   // [4][ROWS*256] raw x
  unsigned short* bc;     // [4][ROWS*16]  raw B|C
};

// input-proj GEMM: ring-3 LDS staging, raw s_barrier + counted s_waitcnt vmcnt(N)
// (never 0 mid-loop): 2 tiles always in flight, no per-phase DMA drain (T4).
// Grid is 1D 2304 with an XCD-aware decode (T1): each XCD owns 16 consecutive A
// row-tiles x all 9 col-tiles x both mats -> A working set (2MB) fits per-XCD L2.
__global__ __launch_bounds__(256) void k_gemm_in(
    const unsigned short* __restrict__ Abase, const unsigned short* __restrict__ Btbase,
    EpiIn ep) {
  __shared__ unsigned short smem[24576];       // 48KB: As[3][4096] | Bs[3][4096]
  const int tid = threadIdx.x;
  const int lane = tid & 63;
  const int wid = tid >> 6;
  const int wm = wid & 1, wn = wid >> 1;
  const int q = lane >> 4, r = lane & 15;
  // XCD-aware decode (bijective: 2304 % 8 == 0)
  const int hbid = blockIdx.x;
  const int xcd = hbid & 7;
  const int j = hbid >> 3;                     // 0..287
  const int m0 = (xcd * 16 + (j & 15)) * 128;  // A row-tile: 16 per XCD
  const int n0 = ((j >> 4) % 9) * 128;
  const int z = j / 144;
  const unsigned short* A = Abase + (long)z * ROWS * 256;
  const unsigned short* Bt = Btbase + (long)z * NPAD * 256;

  // staging descriptors (write-side XOR swizzle matches read-side q^swr)
  int s_row[2], s_ch[2];
  #pragma unroll
  for (int i = 0; i < 2; ++i) {
    int idx = i * 256 + tid;
    s_row[i] = idx >> 2;
    s_ch[i] = (idx & 3) ^ ((s_row[i] >> 1) & 3);
  }

  auto stage = [&](int ti) {
    const int slot = ti % 3;
    const int kt = ti * 32;
    #pragma unroll
    for (int i = 0; i < 2; ++i) {
      gload_lds16(A + (long)(m0 + s_row[i]) * 256 + kt + s_ch[i] * 8,
                  smem + (size_t)slot * 4096 + (size_t)(i * 256 + wid * 64) * 8);
      gload_lds16(Bt + (long)(n0 + s_row[i]) * 256 + kt + s_ch[i] * 8,
                  smem + 12288 + (size_t)slot * 4096 + (size_t)(i * 256 + wid * 64) * 8);
    }
  };

  f32x4 acc[4][4] = {};
  const int swr = (r >> 1) & 3;

  stage(0);
  stage(1);

  #pragma unroll
  for (int i = 0; i < 8; ++i) {
    // wait: all but the NEXT tile's 4 issues done => tile i staged
    if (i < 7) asm volatile("s_waitcnt vmcnt(4)" ::: "memory");
    else       asm volatile("s_waitcnt vmcnt(0)" ::: "memory");
    __builtin_amdgcn_s_barrier();
    __builtin_amdgcn_sched_barrier(0);
    if (i + 2 < 8) stage(i + 2);
    const int slot = i % 3;
    bf16x8 af[4], bfr[4];
    #pragma unroll
    for (int mi = 0; mi < 4; ++mi)
      af[mi] = *(const bf16x8*)&smem[(size_t)slot * 4096 +
                                     ((wm * 64 + mi * 16 + r) * 4 + (q ^ swr)) * 8];
    #pragma unroll
    for (int ni = 0; ni < 4; ++ni)
      bfr[ni] = *(const bf16x8*)&smem[12288 + (size_t)slot * 4096 +
                                      ((wn * 64 + ni * 16 + r) * 4 + (q ^ swr)) * 8];
    __builtin_amdgcn_s_setprio(1);
    #pragma unroll
    for (int mi = 0; mi < 4; ++mi)
      #pragma unroll
      for (int ni = 0; ni < 4; ++ni)
        acc[mi][ni] = __builtin_amdgcn_mfma_f32_16x16x32_bf16(af[mi], bfr[ni], acc[mi][ni], 0, 0, 0);
    __builtin_amdgcn_s_setprio(0);
  }
  __syncthreads();                             // all reads done; staging now dead

  // per-wave transpose region aliases staging: 16 x 72
  unsigned short* tr = smem + wid * (16 * 72);
  #pragma unroll
  for (int mi = 0; mi < 4; ++mi) {
    #pragma unroll
    for (int ni = 0; ni < 4; ++ni)
      #pragma unroll
      for (int j2 = 0; j2 < 4; ++j2)
        tr[(q * 4 + j2) * 72 + ni * 16 + r] = f2bf(acc[mi][ni][j2]);
    asm volatile("s_waitcnt lgkmcnt(0)" ::: "memory");
    #pragma unroll
    for (int pass = 0; pass < 2; ++pass) {
      int rl = pass * 8 + (lane >> 3);
      int c8 = (lane & 7) * 8;
      bf16x8 v = *(const bf16x8*)&tr[rl * 72 + c8];
      int row = m0 + wm * 64 + mi * 16 + rl;
      int col = n0 + wn * 64 + c8;
      int sl = col >= 544;
      int cc = col - (sl ? 544 : 0);
      if (cc < 528) {
        int dir = z * 2 + sl;
        if (cc < 256)
          *(bf16x8*)(ep.zraw + ((long)dir * ROWS + row) * 256 + cc) = v;
        else if (cc < 512)
          *(bf16x8*)(ep.xraw + ((long)dir * ROWS + row) * 256 + cc - 256) = v;
        else
          *(bf16x8*)(ep.bc + ((long)dir * ROWS + row) * 16 + cc - 512) = v;
      }
    }
    asm volatile("s_waitcnt lgkmcnt(0)" ::: "memory");
  }
}

// ---------------- fused out-proj + final GEMM + reduction (ALL 4 dirs) ----------------
// Counted-vmcnt ring-3 pipeline over the GLOBAL 64-tile sequence.
__global__ __launch_bounds__(512) void k_fuse(
    const unsigned short* __restrict__ ybf,      // [4][ROWS][256]
    const unsigned short* __restrict__ Wt_dirs,  // [4][256 n][256 k]
    const unsigned short* __restrict__ Wt_fin,   // [256 c][1024 k] (k = d*256+kk)
    const int* __restrict__ inv,
    float* __restrict__ out) {                   // [ROWS*256] fp32
  __shared__ unsigned short smf[47616];          // Ab[3][2048] | Bb[3][8192] | Tl[64*264]
  unsigned short* Ab = smf;                      // 3 x 4KB
  unsigned short* Bb = smf + 6144;               // 3 x 16KB
  unsigned short* Tl = smf + 30720;              // 33.8KB (bf16 T); aliased fp32 in epilogue
  float* Ttmp = (float*)(smf + 30720);           // 32 x 260 fp32 per half-pass (33.3KB)
  const int tid = threadIdx.x;
  const int lane = tid & 63;
  const int wid = tid >> 6;                      // 0..7
  const int wm = wid & 1, wn = wid >> 1;         // 32-row x 64-col wave tiles
  const int q = lane >> 4, r = lane & 15;
  const int r0 = blockIdx.x * 64;
  const int swr = (r >> 1) & 3;

  // per-thread staging source descriptors (write-side XOR swizzle matches read-side q^swr)
  const int a_row = tid >> 2;                    // tid<256: A row 0..63
  const int a_ch = (tid & 3) ^ ((a_row >> 1) & 3);
  const long a_offH = (long)(r0 + a_row) * 256 + a_ch * 8;
  long a_offV = 0;
  if (tid < 256) a_offV = (long)inv[r0 + a_row] * 256 + a_ch * 8;  // v-row gather
  int b_row[2], b_ch[2];
  #pragma unroll
  for (int rnd = 0; rnd < 2; ++rnd) {
    int idx = rnd * 512 + tid;
    b_row[rnd] = idx >> 2;                       // 0..255
    b_ch[rnd] = (idx & 3) ^ ((b_row[rnd] >> 1) & 3);
  }

  // stage tile g of the 64-tile global sequence into ring slot g%3.
  auto stageT = [&](int g) {
    const int seg = g >> 3, ti = g & 7, kt = ti * 32;
    const int dl = seg >> 1;                     // dir 0..3
    const int slot = g % 3;
    if ((seg & 1) == 0) {                        // G1: A + B(Wt_dirs)
      const long aoff = (dl >= 2) ? a_offV : a_offH;
      if (tid < 256)
        gload_lds16(ybf + (long)dl * ROWS * 256 + aoff + kt,
                    Ab + (size_t)slot * 2048 + (size_t)(wid * 64) * 8);
      #pragma unroll
      for (int rnd = 0; rnd < 2; ++rnd)
        gload_lds16(Wt_dirs + (long)dl * 65536 + (long)b_row[rnd] * 256 + kt + b_ch[rnd] * 8,
                    Bb + (size_t)slot * 8192 + (size_t)(rnd * 512 + wid * 64) * 8);
    } else {                                     // G2: B(Wt_fin) only
      #pragma unroll
      for (int rnd = 0; rnd < 2; ++rnd)
        gload_lds16(Wt_fin + (long)b_row[rnd] * 1024 + dl * 256 + kt + b_ch[rnd] * 8,
                    Bb + (size_t)slot * 8192 + (size_t)(rnd * 512 + wid * 64) * 8);
    }
  };

  f32x4 acc_o[2][4] = {};

  stageT(0);
  stageT(1);

  #pragma unroll
  for (int d = 0; d < 4; ++d) {
    // ---- GEMM1: T = y_d[rows,:] @ Wd (K=256), tiles g = d*16 + 0..7 ----
    f32x4 acc_t[2][4] = {};
    #pragma unroll
    for (int i = 0; i < 8; ++i) {
      const int g = d * 16 + i;
      asm volatile("s_waitcnt vmcnt(2)" ::: "memory");   // tile g fully staged
      __builtin_amdgcn_s_barrier();
      __builtin_amdgcn_sched_barrier(0);
      stageT(g + 2);
      const int slot = g % 3;
      bf16x8 af[2], bfr[4];
      #pragma unroll
      for (int mi = 0; mi < 2; ++mi)
        af[mi] = *(const bf16x8*)&Ab[(size_t)slot * 2048 +
                                     ((wm * 32 + mi * 16 + r) * 4 + (q ^ swr)) * 8];
      #pragma unroll
      for (int ni = 0; ni < 4; ++ni)
        bfr[ni] = *(const bf16x8*)&Bb[(size_t)slot * 8192 +
                                      ((wn * 64 + ni * 16 + r) * 4 + (q ^ swr)) * 8];
      __builtin_amdgcn_s_setprio(1);
      #pragma unroll
      for (int mi = 0; mi < 2; ++mi)
        #pragma unroll
        for (int ni = 0; ni < 4; ++ni)
          acc_t[mi][ni] = __builtin_amdgcn_mfma_f32_16x16x32_bf16(af[mi], bfr[ni], acc_t[mi][ni], 0, 0, 0);
      __builtin_amdgcn_s_setprio(0);
    }
    // ---- write silu(T) to Tl (per-wave disjoint band); published by next barrier.
    #pragma unroll
    for (int mi = 0; mi < 2; ++mi)
      #pragma unroll
      for (int ni = 0; ni < 4; ++ni)
        #pragma unroll
        for (int jj = 0; jj < 4; ++jj)
          Tl[(wm * 32 + mi * 16 + q * 4 + jj) * 264 + wn * 64 + ni * 16 + r] =
              f2bf(siluf(acc_t[mi][ni][jj]));
    asm volatile("s_waitcnt lgkmcnt(0)" ::: "memory");
    // ---- GEMM2: acc_o += T @ Wout col-block d, tiles g = d*16 + 8..15, A from Tl ----
    #pragma unroll
    for (int i = 0; i < 8; ++i) {
      const int g = d * 16 + 8 + i;
      if (g < 63) asm volatile("s_waitcnt vmcnt(2)" ::: "memory");
      else        asm volatile("s_waitcnt vmcnt(0)" ::: "memory");
      __builtin_amdgcn_s_barrier();
      __builtin_amdgcn_sched_barrier(0);
      if (g + 2 < 64) stageT(g + 2);
      const int slot = g % 3;
      const int kt = i * 32;
      bf16x8 af[2], bfr[4];
      #pragma unroll
      for (int mi = 0; mi < 2; ++mi)
        af[mi] = *(const bf16x8*)&Tl[(wm * 32 + mi * 16 + r) * 264 + kt + q * 8];
      #pragma unroll
      for (int ni = 0; ni < 4; ++ni)
        bfr[ni] = *(const bf16x8*)&Bb[(size_t)slot * 8192 +
                                      ((wn * 64 + ni * 16 + r) * 4 + (q ^ swr)) * 8];
      __builtin_amdgcn_s_setprio(1);
      #pragma unroll
      for (int mi = 0; mi < 2; ++mi)
        #pragma unroll
        for (int ni = 0; ni < 4; ++ni)
          acc_o[mi][ni] = __builtin_amdgcn_mfma_f32_16x16x32_bf16(af[mi], bfr[ni], acc_o[mi][ni], 0, 0, 0);
      __builtin_amdgcn_s_setprio(0);
    }
  }

  // ---- epilogue: fp32 out via two half-row LDS transpose passes (Ttmp aliases Tl) ----
  __syncthreads();                               // all GEMM2 Tl reads consumed
  #pragma unroll
  for (int h = 0; h < 2; ++h) {
    if (wm == h) {
      #pragma unroll
      for (int mi = 0; mi < 2; ++mi)
        #pragma unroll
        for (int ni = 0; ni < 4; ++ni)
          #pragma unroll
          for (int jj = 0; jj < 4; ++jj)
            Ttmp[(mi * 16 + q * 4 + jj) * 260 + wn * 64 + ni * 16 + r] = acc_o[mi][ni][jj];
    }
    __syncthreads();
    #pragma unroll
    for (int pass = 0; pass < 4; ++pass) {
      int id = pass * 512 + tid;                 // 32 rows x 64 float4
      int row = id >> 6, c4 = (id & 63) * 4;
      float4 v = *(const float4*)&Ttmp[row * 260 + c4];
      *(float4*)(out + (long)(r0 + h * 32 + row) * 256 + c4) = v;
    }
    if (h == 0) __syncthreads();                 // stores read before overwrite
  }
}

// ---------------- scan kernels (vectorized: lane owns 4 consecutive columns) ----------------
struct ScanP {
  const unsigned short* xraw;  // [4][ROWS*256] raw (silu applied here)
  const unsigned short* zraw;
  const unsigned short* bc;    // [4][ROWS*16] raw
  const float* dtv;            // [16][ROWS]  (dir*4+h)
  const float* dA;
  const float* D[4];
};

// S/carry layout: per (d, c, b) a contiguous 2048-float vector, element e = col*8 + n.
// Lane p owns cols 4p..4p+3 (head h = p>>4) -> writes/reads 32 contiguous floats at p*32.
// P layout: [(d*NCHUNK+c)*2+b][h] (4 floats).

// phase 1: per-chunk (64 steps) local scan from zero; ushort4 x loads (8B/lane).
__global__ __launch_bounds__(64) void k_scan1(ScanP sp, float* __restrict__ S,
                                              float* __restrict__ P) {
  __shared__ __align__(16) float Bst[CHUNK][8];
  __shared__ float dAs[CHUNK][4];
  __shared__ float dts[CHUNK][4];
  const int p = threadIdx.x;
  const int c = blockIdx.x;
  const int db = blockIdx.y;                   // d*2+b
  const int d = db >> 1, b = db & 1;
  const int rev = d & 1;
  const int t0 = c * CHUNK;
  {
    const int t = t0 + p;                      // p covers all 64 steps
    const int l = rev ? (L_N - 1 - t) : t;
    const int row = (b << 13) + l;
    uint4 bv = *(const uint4*)(sp.bc + ((long)d * ROWS + row) * 16);
    const unsigned short* bu = (const unsigned short*)&bv;
    #pragma unroll
    for (int n = 0; n < 8; ++n) Bst[p][n] = siluf(bf2f(bu[n]));
    #pragma unroll
    for (int hh = 0; hh < 4; ++hh) {
      dts[p][hh] = sp.dtv[((long)d * 4 + hh) * ROWS + row];
      dAs[p][hh] = sp.dA[((long)d * 4 + hh) * ROWS + row];
    }
  }
  __syncthreads();

  const int h = p >> 4;
  float st[4][8] = {};
  float cumdA = 1.f;
  const int l0 = rev ? (L_N - 1 - t0) : t0;
  const unsigned short* xp = sp.xraw + ((long)d * ROWS + (b << 13) + l0) * 256 + 4 * p;
  const long stp = rev ? -256L : 256L;

  ushort4 xa[4], xb[4];
  #pragma unroll
  for (int j = 0; j < 4; ++j) xa[j] = *(const ushort4*)(xp + (long)j * stp);
  #pragma unroll
  for (int g = 0; g < CHUNK / 4; ++g) {
    if (g < CHUNK / 4 - 1) {
      #pragma unroll
      for (int j = 0; j < 4; ++j)
        xb[j] = *(const ushort4*)(xp + (long)((g + 1) * 4 + j) * stp);
    }
    #pragma unroll
    for (int j = 0; j < 4; ++j) {
      const int s = g * 4 + j;
      const float dA = dAs[s][h];
      const float dt = dts[s][h];
      cumdA *= dA;
      const unsigned short* xu = (const unsigned short*)&xa[j];
      #pragma unroll
      for (int cc = 0; cc < 4; ++cc) {
        float xd = siluf(bf2f(xu[cc])) * dt;
        #pragma unroll
        for (int n = 0; n < 8; ++n)
          st[cc][n] = fmaf(dA, st[cc][n], xd * Bst[s][n]);
      }
    }
    #pragma unroll
    for (int j = 0; j < 4; ++j) xa[j] = xb[j];
  }
  float* Sp = S + ((long)(d * NCHUNK + c) * 2 + b) * 2048 + p * 32;
  #pragma unroll
  for (int cc = 0; cc < 4; ++cc) {
    f32x4 v0 = {st[cc][0], st[cc][1], st[cc][2], st[cc][3]};
    f32x4 v1 = {st[cc][4], st[cc][5], st[cc][6], st[cc][7]};
    *(f32x4*)(Sp + cc * 8) = v0;
    *(f32x4*)(Sp + cc * 8 + 4) = v1;
  }
  if ((p & 15) == 0) P[((long)(d * NCHUNK + c) * 2 + b) * 4 + h] = cumdA;
}

// phase 2a: group-local combine; grid 256 blocks = (d,b,g,q); q selects 512-elem slice
// (h = q since elements 512*q..512*q+511 all belong to head q).
__global__ __launch_bounds__(512) void k_scan2a(const float* __restrict__ S,
                                                const float* __restrict__ P,
                                                float* __restrict__ carry_loc,
                                                float* __restrict__ Sg,
                                                float* __restrict__ Pg) {
  __shared__ float Pl[GRP];
  const int tid = threadIdx.x;
  const int gid = blockIdx.x;                   // d*64 + b*32 + g*4 + q
  const int d = gid >> 6;
  const int b = (gid >> 5) & 1;
  const int g = (gid >> 2) & 7;
  const int q = gid & 3;                        // = head h
  if (tid < GRP)
    Pl[tid] = P[((long)(d * NCHUNK + g * GRP + tid) * 2 + b) * 4 + q];
  __syncthreads();
  const int e = q * 512 + tid;
  float cy = 0.f;
  #pragma unroll
  for (int i = 0; i < GRP; ++i) {
    const int c = g * GRP + i;
    const long base = ((long)(d * NCHUNK + c) * 2 + b) * 2048;
    carry_loc[base + e] = cy;
    const float Sv = S[base + e];
    cy = fmaf(Pl[i], cy, Sv);
  }
  Sg[((long)(d * NGRP + g) * 2 + b) * 2048 + e] = cy;
  if (tid == 0) {
    float pp = 1.f;
    #pragma unroll
    for (int i = 0; i < GRP; ++i) pp *= Pl[i];
    Pg[((long)(d * NGRP + g) * 2 + b) * 4 + q] = pp;
  }
}

// phase 2b: sequential combine over 8 groups; grid 32 blocks = (d,b,q)
__global__ __launch_bounds__(512) void k_scan2b(const float* __restrict__ Sg,
                                                const float* __restrict__ Pg,
                                                float* __restrict__ gcarry) {
  __shared__ float Pgl[NGRP];
  const int tid = threadIdx.x;
  const int gid = blockIdx.x;                   // d*8 + b*4 + q
  const int d = gid >> 3;
  const int b = (gid >> 2) & 1;
  const int q = gid & 3;
  if (tid < NGRP)
    Pgl[tid] = Pg[((long)(d * NGRP + tid) * 2 + b) * 4 + q];
  __syncthreads();
  const int e = q * 512 + tid;
  float cy = 0.f;
  #pragma unroll
  for (int g = 0; g < NGRP; ++g) {
    const long base = ((long)(d * NGRP + g) * 2 + b) * 2048;
    gcarry[base + e] = cy;
    const float Sv = Sg[base + e];
    cy = fmaf(Pgl[g], cy, Sv);
  }
}

// phase 3: re-scan with carry-in, produce gated y (ushort4 loads/stores, 8B/lane).
// Full carry = carry_loc + prefixP(group) * gcarry.
__global__ __launch_bounds__(64) void k_scan3(ScanP sp,
                                              const float* __restrict__ carry_loc,
                                              const float* __restrict__ gcarry,
                                              const float* __restrict__ Pc,
                                              unsigned short* __restrict__ ybf) {
  __shared__ __align__(16) float Bst[CHUNK][8];
  __shared__ __align__(16) float Cst[CHUNK][8];
  __shared__ float dAs[CHUNK][4];
  __shared__ float dts[CHUNK][4];
  __shared__ float Pgr[GRP][4];
  const int p = threadIdx.x;
  const int c = blockIdx.x;
  const int db = blockIdx.y;                   // d*2+b
  const int d = db >> 1, b = db & 1;
  const int rev = d & 1;
  const int t0 = c * CHUNK;
  const int grp = c >> 4, ii = c & 15;
  if (p < 64) {                                // stage Pgr[16][4]
    int k = p >> 2, hh = p & 3;
    Pgr[k][hh] = Pc[((long)(d * NCHUNK + grp * GRP + k) * 2 + b) * 4 + hh];
  }
  {
    const int t = t0 + p;
    const int l = rev ? (L_N - 1 - t) : t;
    const int row = (b << 13) + l;
    const unsigned short* bp = sp.bc + ((long)d * ROWS + row) * 16;
    uint4 bv = *(const uint4*)bp;
    uint4 cv = *(const uint4*)(bp + 8);
    const unsigned short* bu = (const unsigned short*)&bv;
    const unsigned short* cu = (const unsigned short*)&cv;
    #pragma unroll
    for (int n = 0; n < 8; ++n) Bst[p][n] = siluf(bf2f(bu[n]));
    #pragma unroll
    for (int n = 0; n < 8; ++n) Cst[p][n] = siluf(bf2f(cu[n]));
    #pragma unroll
    for (int hh = 0; hh < 4; ++hh) {
      dts[p][hh] = sp.dtv[((long)d * 4 + hh) * ROWS + row];
      dAs[p][hh] = sp.dA[((long)d * 4 + hh) * ROWS + row];
    }
  }
  __syncthreads();

  const int h = p >> 4;
  const float Dv = sp.D[d][h];
  float pref = 1.f;
  for (int k = 0; k < ii; ++k) pref *= Pgr[k][h];
  float st[4][8];
  {
    const float* clp = carry_loc + ((long)(d * NCHUNK + c) * 2 + b) * 2048 + p * 32;
    const float* gcp = gcarry + ((long)(d * NGRP + grp) * 2 + b) * 2048 + p * 32;
    #pragma unroll
    for (int cc = 0; cc < 4; ++cc)
      #pragma unroll
      for (int n = 0; n < 8; ++n)
        st[cc][n] = fmaf(pref, gcp[cc * 8 + n], clp[cc * 8 + n]);
  }

  const int l0 = rev ? (L_N - 1 - t0) : t0;
  const long base = (long)(b << 13) + l0;
  const unsigned short* xp = sp.xraw + ((long)d * ROWS + base) * 256 + 4 * p;
  const unsigned short* zp = sp.zraw + ((long)d * ROWS + base) * 256 + 4 * p;
  unsigned short* yp = ybf + ((long)d * ROWS + base) * 256 + 4 * p;
  const long stp = rev ? -256L : 256L;

  ushort4 xa[4], xb[4], za[4], zb[4];
  #pragma unroll
  for (int j = 0; j < 4; ++j) {
    xa[j] = *(const ushort4*)(xp + (long)j * stp);
    za[j] = *(const ushort4*)(zp + (long)j * stp);
  }
  #pragma unroll
  for (int g = 0; g < CHUNK / 4; ++g) {
    if (g < CHUNK / 4 - 1) {
      #pragma unroll
      for (int j = 0; j < 4; ++j) {
        xb[j] = *(const ushort4*)(xp + (long)((g + 1) * 4 + j) * stp);
        zb[j] = *(const ushort4*)(zp + (long)((g + 1) * 4 + j) * stp);
      }
    }
    #pragma unroll
    for (int j = 0; j < 4; ++j) {
      const int s = g * 4 + j;
      const float dA = dAs[s][h];
      const float dt = dts[s][h];
      const unsigned short* xu = (const unsigned short*)&xa[j];
      const unsigned short* zu = (const unsigned short*)&za[j];
      ushort4 o;
      unsigned short* ou = (unsigned short*)&o;
      #pragma unroll
      for (int cc = 0; cc < 4; ++cc) {
        float xv = siluf(bf2f(xu[cc]));
        float zv = siluf(bf2f(zu[cc]));
        float xd = xv * dt;
        #pragma unroll
        for (int n = 0; n < 8; ++n)
          st[cc][n] = fmaf(dA, st[cc][n], xd * Bst[s][n]);
        float y01 = fmaf(st[cc][1], Cst[s][1], st[cc][0] * Cst[s][0]);
        float y23 = fmaf(st[cc][3], Cst[s][3], st[cc][2] * Cst[s][2]);
        float y45 = fmaf(st[cc][5], Cst[s][5], st[cc][4] * Cst[s][4]);
        float y67 = fmaf(st[cc][7], Cst[s][7], st[cc][6] * Cst[s][6]);
        float y = (y01 + y23) + (y45 + y67);
        y = fmaf(Dv, xv, y) * zv;
        ou[cc] = f2bf(y);
      }
      *(ushort4*)(yp + (long)s * stp) = o;
    }
    #pragma unroll
    for (int j = 0; j < 4; ++j) { xa[j] = xb[j]; za[j] = zb[j]; }
  }
}

// ---------------- launch ----------------
extern "C" void kernel_launch(void* const* d_in, const int* in_sizes, int n_in,
                              void* d_out, int out_size, void* d_ws, size_t ws_size,
                              hipStream_t stream) {
  const float* x_H = (const float*)d_in[0];
  const float* x_V = (const float*)d_in[1];
  const float* W_in_H = (const float*)d_in[2];
  const float* W_in_V = (const float*)d_in[3];
  const float* W_out_HF = (const float*)d_in[4];
  const float* W_out_HB = (const float*)d_in[5];
  const float* W_out_VF = (const float*)d_in[6];
  const float* W_out_VB = (const float*)d_in[7];
  const float* W_out = (const float*)d_in[8];
  const float* dt_bias_HF = (const float*)d_in[9];
  const float* A_log_HF = (const float*)d_in[10];
  const float* D_HF = (const float*)d_in[11];
  const float* dt_bias_HB = (const float*)d_in[12];
  const float* A_log_HB = (const float*)d_in[13];
  const float* D_HB = (const float*)d_in[14];
  const float* dt_bias_VF = (const float*)d_in[15];
  const float* A_log_VF = (const float*)d_in[16];
  const float* D_VF = (const float*)d_in[17];
  const float* dt_bias_VB = (const float*)d_in[18];
  const float* A_log_VB = (const float*)d_in[19];
  const float* D_VB = (const float*)d_in[20];
  const int* v2h = (const int*)d_in[21];

  char* ws = (char*)d_ws;
  size_t off = 0;
  auto alloc = [&](size_t bytes) {
    void* pp = ws + off;
    off = (off + bytes + 255) & ~(size_t)255;
    return pp;
  };
  unsigned short* xbf = (unsigned short*)alloc((size_t)2 * ROWS * 256 * 2);      // [2 mats]
  unsigned short* Wt_in = (unsigned short*)alloc((size_t)2 * NPAD * 256 * 2);    // [2 mats]
  unsigned short* Wt_dirs = (unsigned short*)alloc((size_t)4 * 65536 * 2);
  unsigned short* Wt_fin = (unsigned short*)alloc((size_t)256 * 1024 * 2);
  unsigned short* zraw = (unsigned short*)alloc((size_t)4 * ROWS * 256 * 2);
  unsigned short* xraw = (unsigned short*)alloc((size_t)4 * ROWS * 256 * 2);
  unsigned short* bc = (unsigned short*)alloc((size_t)4 * ROWS * 16 * 2);
  float* dtv_arr = (float*)alloc((size_t)16 * ROWS * 4);
  float* dA_arr = (float*)alloc((size_t)16 * ROWS * 4);
  unsigned short* ybf = (unsigned short*)alloc((size_t)4 * ROWS * 256 * 2);
  float* S = (float*)alloc((size_t)4 * NCHUNK * 2 * 2048 * 4);
  float* P = (float*)alloc((size_t)4 * NCHUNK * 2 * 4 * 4);
  float* carry_loc = (float*)alloc((size_t)4 * NCHUNK * 2 * 2048 * 4);
  float* Sg = (float*)alloc((size_t)4 * NGRP * 2 * 2048 * 4);
  float* Pg = (float*)alloc((size_t)4 * NGRP * 2 * 4 * 4);
  float* gcarry = (float*)alloc((size_t)4 * NGRP * 2 * 2048 * 4);
  int* inv = (int*)alloc((size_t)ROWS * 4);

  ScanConsts sc;
  sc.dt_bias[0] = dt_bias_HF; sc.dt_bias[1] = dt_bias_HB;
  sc.dt_bias[2] = dt_bias_VF; sc.dt_bias[3] = dt_bias_VB;
  sc.A_log[0] = A_log_HF; sc.A_log[1] = A_log_HB;
  sc.A_log[2] = A_log_VF; sc.A_log[3] = A_log_VB;
  sc.D[0] = D_HF; sc.D[1] = D_HB; sc.D[2] = D_VF; sc.D[3] = D_VB;

  P4 wdirs;  // cat order: dir0 HF->W_out_HB, dir1 HB->W_out_HF, dir2 VF->W_out_VB, dir3 VB->W_out_VF
  wdirs.p[0] = W_out_HB; wdirs.p[1] = W_out_HF; wdirs.p[2] = W_out_VB; wdirs.p[3] = W_out_VF;

  // merged prep: dtfix (+x cvt) | weights | inv
  k_prep<<<5440, 256, 0, stream>>>(x_H, x_V, W_in_H, W_in_V, wdirs, W_out, v2h, sc,
                                   xbf, dtv_arr, dA_arr, Wt_in, Wt_dirs, Wt_fin, inv);

  EpiIn ep; ep.zraw = zraw; ep.xraw = xraw; ep.bc = bc;

  // input GEMMs (XCD-aware 1D grid, counted-vmcnt ring-3), routing epilogue
  k_gemm_in<<<2304, 256, 0, stream>>>(xbf, Wt_in, ep);

  ScanP sp;
  sp.xraw = xraw; sp.zraw = zraw; sp.bc = bc; sp.dtv = dtv_arr; sp.dA = dA_arr;
  sp.D[0] = D_HF; sp.D[1] = D_HB; sp.D[2] = D_VF; sp.D[3] = D_VB;

  k_scan1<<<dim3(NCHUNK, 8), 64, 0, stream>>>(sp, S, P);
  k_scan2a<<<256, 512, 0, stream>>>(S, P, carry_loc, Sg, Pg);
  k_scan2b<<<32, 512, 0, stream>>>(Sg, Pg, gcarry);
  k_scan3<<<dim3(NCHUNK, 8), 64, 0, stream>>>(sp, carry_loc, gcarry, P, ybf);

  // fused out-proj + final GEMM + 4-dir reduction -> fp32 d_out
  k_fuse<<<256, 512, 0, stream>>>(ybf, Wt_dirs, Wt_fin, inv, (float*)d_out);

  (void)in_sizes; (void)n_in; (void)out_size; (void)ws_size;
}

// Round 12
// 237.639 us; speedup vs baseline: 1.8067x; 1.8067x over previous
//
#include <hip/hip_runtime.h>
#include <hip/hip_bf16.h>

// ---------------- problem constants ----------------
#define B_N 2
#define L_N 8192
#define ROWS 16384                // B_N * L_N
#define CHUNK 64
#define NCHUNK 128                // L_N / CHUNK
#define GRP 16                    // chunks per combine group
#define NGRP 8                    // NCHUNK / GRP
#define NPAD 1152                 // input-proj N padded: 2 x 544 + pad to 9*128

typedef __bf16 bf16x8 __attribute__((ext_vector_type(8)));
typedef float f32x4 __attribute__((ext_vector_type(4)));

// fast silu: 1-ulp rcp instead of IEEE divide
__device__ __forceinline__ float siluf(float v) {
  return v * __builtin_amdgcn_rcpf(1.f + __expf(-v));
}
__device__ __forceinline__ float softplusf_(float v) {
  return fmaxf(v, 0.f) + log1pf(__expf(-fabsf(v)));
}
// native bf16 convert (gfx950 HW cvt, RNE)
__device__ __forceinline__ unsigned short f2bf(float v) {
  union { __bf16 b; unsigned short u; } x;
  x.b = (__bf16)v;
  return x.u;
}
__device__ __forceinline__ float bf2f(unsigned short u) {
  union { unsigned u; float f; } x; x.u = ((unsigned)u) << 16;
  return x.f;
}

// async global->LDS, 16B per lane, LDS dest = wave-uniform base + lane*16
__device__ __forceinline__ void gload_lds16(const unsigned short* g, unsigned short* l) {
  __builtin_amdgcn_global_load_lds(
      (const __attribute__((address_space(1))) unsigned int*)g,
      (__attribute__((address_space(3))) unsigned int*)l, 16, 0, 0);
}

struct P4 { const float* p[4]; };
struct ScanConsts {
  const float* dt_bias[4];
  const float* A_log[4];
  const float* D[4];
};

// ---------------- merged prep + dtfix ----------------
// blocks [0,1024): dtfix (mat = bid>>9, rowblock = bid&511) — exact fp32 dt dot with LDS
//   staging, writes dtv/dA and xbf (bf16 cvt of x).
// blocks [1024,3328): Wt_in; [3328,4352): Wt_dirs; [4352,5376): Wt_fin; [5376,5440): inv
__global__ __launch_bounds__(256) void k_prep(
    const float* __restrict__ xH, const float* __restrict__ xV,
    const float* __restrict__ WH, const float* __restrict__ WV,
    P4 ws, const float* __restrict__ W_out, const int* __restrict__ v2h, ScanConsts sc,
    unsigned short* __restrict__ xbf, float* __restrict__ dtv_arr, float* __restrict__ dA_arr,
    unsigned short* __restrict__ Wt_in, unsigned short* __restrict__ Wt_dirs,
    unsigned short* __restrict__ Wt_fin, int* __restrict__ inv) {
  __shared__ float xs[32][257];
  __shared__ float Wsm[8][260];
  int bid = blockIdx.x;
  int tid = threadIdx.x;
  if (bid < 1024) {
    const int mat = bid >> 9;
    const float* x = mat ? xV : xH;
    const float* W = mat ? WV : WH;
    const int r0 = (bid & 511) * 32;
    for (int i = tid; i < 2048; i += 256) {
      int c = i >> 8, k = i & 255;            // c = sl*4+h
      int sl = c >> 2, h = c & 3;
      Wsm[c][k] = W[(long)k * 1064 + sl * 532 + 528 + h];
    }
    for (int i = tid; i < 32 * 64; i += 256) {
      int rl = i >> 6, kq = (i & 63) * 4;
      float4 v = *(const float4*)(x + (long)(r0 + rl) * 256 + kq);
      xs[rl][kq + 0] = v.x; xs[rl][kq + 1] = v.y; xs[rl][kq + 2] = v.z; xs[rl][kq + 3] = v.w;
    }
    __syncthreads();
    for (int i = tid; i < 32 * 64; i += 256) {
      int rl = i >> 6, kq = (i & 63) * 4;
      ushort4 o;
      o.x = f2bf(xs[rl][kq + 0]);
      o.y = f2bf(xs[rl][kq + 1]);
      o.z = f2bf(xs[rl][kq + 2]);
      o.w = f2bf(xs[rl][kq + 3]);
      *(ushort4*)(xbf + (size_t)mat * ROWS * 256 + (long)(r0 + rl) * 256 + kq) = o;
    }
    const int rl = tid >> 3, c = tid & 7;
    float s = 0.f;
    #pragma unroll 8
    for (int k = 0; k < 256; ++k) s = fmaf(xs[rl][k], Wsm[c][k], s);
    const int sl = c >> 2, h = c & 3;
    const int dir = mat * 2 + sl;
    float dtv = softplusf_(s + sc.dt_bias[dir][h]);
    float dAv = __expf(dtv * (-__expf(sc.A_log[dir][h])));
    long o = ((long)dir * 4 + h) * ROWS + (r0 + rl);
    dtv_arr[o] = dtv;
    dA_arr[o] = dAv;
  } else if (bid < 3328) {
    int i = (bid - 1024) * 256 + tid;         // 2*1152*256
    int z = i / (NPAD * 256);
    int rem = i - z * (NPAD * 256);
    int n = rem >> 8, k = rem & 255;
    const float* W = z ? WV : WH;
    int sl = n >= 544;
    int cc = n - (sl ? 544 : 0);
    float v = (cc < 532) ? W[(long)k * 1064 + sl * 532 + cc] : 0.f;
    Wt_in[i] = f2bf(v);
  } else if (bid < 4352) {
    int i = (bid - 3328) * 256 + tid;         // 4*65536
    int d = i >> 16;
    int rem = i & 65535;
    int n = rem >> 8, k = rem & 255;
    Wt_dirs[i] = f2bf(ws.p[d][(long)k * 256 + n]);
  } else if (bid < 5376) {
    int i = (bid - 4352) * 256 + tid;         // 256*1024, i = n*1024+k
    int n = i >> 10, k = i & 1023;
    Wt_fin[i] = f2bf(W_out[(long)k * 256 + n]);
  } else {
    int m = (bid - 5376) * 256 + tid;
    if (m < ROWS) {
      int b = m >> 13;
      inv[b * L_N + v2h[m]] = m;              // inv[h-row] = v-row
    }
  }
}

// ---------------- bf16 MFMA GEMM (128x128 tile, BK=32, counted-vmcnt ring-3) ----------------
struct EpiIn {
  unsigned short* zraw;   // [4][ROWS*256] raw z (silu applied in scans)
  unsigned short* xraw;   // [4][ROWS*256] raw x
  unsigned short* bc;     // [4][ROWS*16]  raw B|C
};

// input-proj GEMM: ring-3 LDS staging, raw s_barrier + counted s_waitcnt vmcnt(N)
// (never 0 mid-loop): 2 tiles always in flight, no per-phase DMA drain (T4).
// Grid is 1D 2304 with an XCD-aware decode (T1): each XCD owns 16 consecutive A
// row-tiles x all 9 col-tiles x both mats -> A working set (2MB) fits per-XCD L2.
__global__ __launch_bounds__(256) void k_gemm_in(
    const unsigned short* __restrict__ Abase, const unsigned short* __restrict__ Btbase,
    EpiIn ep) {
  __shared__ unsigned short smem[24576];       // 48KB: As[3][4096] | Bs[3][4096]
  const int tid = threadIdx.x;
  const int lane = tid & 63;
  const int wid = tid >> 6;
  const int wm = wid & 1, wn = wid >> 1;
  const int q = lane >> 4, r = lane & 15;
  // XCD-aware decode (bijective: 2304 % 8 == 0)
  const int hbid = blockIdx.x;
  const int xcd = hbid & 7;
  const int j = hbid >> 3;                     // 0..287
  const int m0 = (xcd * 16 + (j & 15)) * 128;  // A row-tile: 16 per XCD
  const int n0 = ((j >> 4) % 9) * 128;
  const int z = j / 144;
  const unsigned short* A = Abase + (long)z * ROWS * 256;
  const unsigned short* Bt = Btbase + (long)z * NPAD * 256;

  // staging descriptors (write-side XOR swizzle matches read-side q^swr)
  int s_row[2], s_ch[2];
  #pragma unroll
  for (int i = 0; i < 2; ++i) {
    int idx = i * 256 + tid;
    s_row[i] = idx >> 2;
    s_ch[i] = (idx & 3) ^ ((s_row[i] >> 1) & 3);
  }

  auto stage = [&](int ti) {
    const int slot = ti % 3;
    const int kt = ti * 32;
    #pragma unroll
    for (int i = 0; i < 2; ++i) {
      gload_lds16(A + (long)(m0 + s_row[i]) * 256 + kt + s_ch[i] * 8,
                  smem + (size_t)slot * 4096 + (size_t)(i * 256 + wid * 64) * 8);
      gload_lds16(Bt + (long)(n0 + s_row[i]) * 256 + kt + s_ch[i] * 8,
                  smem + 12288 + (size_t)slot * 4096 + (size_t)(i * 256 + wid * 64) * 8);
    }
  };

  f32x4 acc[4][4] = {};
  const int swr = (r >> 1) & 3;

  stage(0);
  stage(1);

  #pragma unroll
  for (int i = 0; i < 8; ++i) {
    // wait: all but the NEXT tile's 4 issues done => tile i staged
    if (i < 7) asm volatile("s_waitcnt vmcnt(4)" ::: "memory");
    else       asm volatile("s_waitcnt vmcnt(0)" ::: "memory");
    __builtin_amdgcn_s_barrier();
    __builtin_amdgcn_sched_barrier(0);
    if (i + 2 < 8) stage(i + 2);
    const int slot = i % 3;
    bf16x8 af[4], bfr[4];
    #pragma unroll
    for (int mi = 0; mi < 4; ++mi)
      af[mi] = *(const bf16x8*)&smem[(size_t)slot * 4096 +
                                     ((wm * 64 + mi * 16 + r) * 4 + (q ^ swr)) * 8];
    #pragma unroll
    for (int ni = 0; ni < 4; ++ni)
      bfr[ni] = *(const bf16x8*)&smem[12288 + (size_t)slot * 4096 +
                                      ((wn * 64 + ni * 16 + r) * 4 + (q ^ swr)) * 8];
    __builtin_amdgcn_s_setprio(1);
    #pragma unroll
    for (int mi = 0; mi < 4; ++mi)
      #pragma unroll
      for (int ni = 0; ni < 4; ++ni)
        acc[mi][ni] = __builtin_amdgcn_mfma_f32_16x16x32_bf16(af[mi], bfr[ni], acc[mi][ni], 0, 0, 0);
    __builtin_amdgcn_s_setprio(0);
  }
  __syncthreads();                             // all reads done; staging now dead

  // per-wave transpose region aliases staging: 16 x 72
  unsigned short* tr = smem + wid * (16 * 72);
  #pragma unroll
  for (int mi = 0; mi < 4; ++mi) {
    #pragma unroll
    for (int ni = 0; ni < 4; ++ni)
      #pragma unroll
      for (int j2 = 0; j2 < 4; ++j2)
        tr[(q * 4 + j2) * 72 + ni * 16 + r] = f2bf(acc[mi][ni][j2]);
    asm volatile("s_waitcnt lgkmcnt(0)" ::: "memory");
    #pragma unroll
    for (int pass = 0; pass < 2; ++pass) {
      int rl = pass * 8 + (lane >> 3);
      int c8 = (lane & 7) * 8;
      bf16x8 v = *(const bf16x8*)&tr[rl * 72 + c8];
      int row = m0 + wm * 64 + mi * 16 + rl;
      int col = n0 + wn * 64 + c8;
      int sl = col >= 544;
      int cc = col - (sl ? 544 : 0);
      if (cc < 528) {
        int dir = z * 2 + sl;
        if (cc < 256)
          *(bf16x8*)(ep.zraw + ((long)dir * ROWS + row) * 256 + cc) = v;
        else if (cc < 512)
          *(bf16x8*)(ep.xraw + ((long)dir * ROWS + row) * 256 + cc - 256) = v;
        else
          *(bf16x8*)(ep.bc + ((long)dir * ROWS + row) * 16 + cc - 512) = v;
      }
    }
    asm volatile("s_waitcnt lgkmcnt(0)" ::: "memory");
  }
}

// ---------------- fused out-proj + final GEMM + reduction (ALL 4 dirs) ----------------
// Counted-vmcnt ring-3 pipeline over the GLOBAL 64-tile sequence
// (d0.G1 x8, d0.G2 x8, d1.G1 x8, ... d3.G2 x8). acc_o accumulates across all 4 dirs
// in fp32; epilogue writes fp32 d_out directly. V-dirs' A rows are gathered via inv
// at staging time. LDS ~93KB -> 1 block/CU, 8 waves; grid = 256 blocks = 1/CU.
__global__ __launch_bounds__(512) void k_fuse(
    const unsigned short* __restrict__ ybf,      // [4][ROWS][256]
    const unsigned short* __restrict__ Wt_dirs,  // [4][256 n][256 k]
    const unsigned short* __restrict__ Wt_fin,   // [256 c][1024 k] (k = d*256+kk)
    const int* __restrict__ inv,
    float* __restrict__ out) {                   // [ROWS*256] fp32
  __shared__ unsigned short smf[47616];          // Ab[3][2048] | Bb[3][8192] | Tl[64*264]
  unsigned short* Ab = smf;                      // 3 x 4KB
  unsigned short* Bb = smf + 6144;               // 3 x 16KB
  unsigned short* Tl = smf + 30720;              // 33.8KB (bf16 T); aliased fp32 in epilogue
  float* Ttmp = (float*)(smf + 30720);           // 32 x 260 fp32 per half-pass (33.3KB)
  const int tid = threadIdx.x;
  const int lane = tid & 63;
  const int wid = tid >> 6;                      // 0..7
  const int wm = wid & 1, wn = wid >> 1;         // 32-row x 64-col wave tiles
  const int q = lane >> 4, r = lane & 15;
  const int r0 = blockIdx.x * 64;
  const int swr = (r >> 1) & 3;

  // per-thread staging source descriptors (write-side XOR swizzle matches read-side q^swr)
  const int a_row = tid >> 2;                    // tid<256: A row 0..63
  const int a_ch = (tid & 3) ^ ((a_row >> 1) & 3);
  const long a_offH = (long)(r0 + a_row) * 256 + a_ch * 8;
  long a_offV = 0;
  if (tid < 256) a_offV = (long)inv[r0 + a_row] * 256 + a_ch * 8;  // v-row gather
  int b_row[2], b_ch[2];
  #pragma unroll
  for (int rnd = 0; rnd < 2; ++rnd) {
    int idx = rnd * 512 + tid;
    b_row[rnd] = idx >> 2;                       // 0..255
    b_ch[rnd] = (idx & 3) ^ ((b_row[rnd] >> 1) & 3);
  }

  // stage tile g of the 64-tile global sequence into ring slot g%3.
  // g must be compile-time (loops fully unrolled) so dir selection folds.
  auto stageT = [&](int g) {
    const int seg = g >> 3, ti = g & 7, kt = ti * 32;
    const int dl = seg >> 1;                     // dir 0..3
    const int slot = g % 3;
    if ((seg & 1) == 0) {                        // G1: A + B(Wt_dirs)
      const long aoff = (dl >= 2) ? a_offV : a_offH;
      if (tid < 256)
        gload_lds16(ybf + (long)dl * ROWS * 256 + aoff + kt,
                    Ab + (size_t)slot * 2048 + (size_t)(wid * 64) * 8);
      #pragma unroll
      for (int rnd = 0; rnd < 2; ++rnd)
        gload_lds16(Wt_dirs + (long)dl * 65536 + (long)b_row[rnd] * 256 + kt + b_ch[rnd] * 8,
                    Bb + (size_t)slot * 8192 + (size_t)(rnd * 512 + wid * 64) * 8);
    } else {                                     // G2: B(Wt_fin) only
      #pragma unroll
      for (int rnd = 0; rnd < 2; ++rnd)
        gload_lds16(Wt_fin + (long)b_row[rnd] * 1024 + dl * 256 + kt + b_ch[rnd] * 8,
                    Bb + (size_t)slot * 8192 + (size_t)(rnd * 512 + wid * 64) * 8);
    }
  };

  f32x4 acc_o[2][4] = {};

  stageT(0);
  stageT(1);

  #pragma unroll
  for (int d = 0; d < 4; ++d) {
    // ---- GEMM1: T = y_d[rows,:] @ Wd (K=256), tiles g = d*16 + 0..7 ----
    f32x4 acc_t[2][4] = {};
    #pragma unroll
    for (int i = 0; i < 8; ++i) {
      const int g = d * 16 + i;
      asm volatile("s_waitcnt vmcnt(2)" ::: "memory");   // tile g fully staged
      __builtin_amdgcn_s_barrier();
      __builtin_amdgcn_sched_barrier(0);
      stageT(g + 2);                             // g+2 <= 57 < 64 always here
      const int slot = g % 3;
      bf16x8 af[2], bfr[4];
      #pragma unroll
      for (int mi = 0; mi < 2; ++mi)
        af[mi] = *(const bf16x8*)&Ab[(size_t)slot * 2048 +
                                     ((wm * 32 + mi * 16 + r) * 4 + (q ^ swr)) * 8];
      #pragma unroll
      for (int ni = 0; ni < 4; ++ni)
        bfr[ni] = *(const bf16x8*)&Bb[(size_t)slot * 8192 +
                                      ((wn * 64 + ni * 16 + r) * 4 + (q ^ swr)) * 8];
      __builtin_amdgcn_s_setprio(1);
      #pragma unroll
      for (int mi = 0; mi < 2; ++mi)
        #pragma unroll
        for (int ni = 0; ni < 4; ++ni)
          acc_t[mi][ni] = __builtin_amdgcn_mfma_f32_16x16x32_bf16(af[mi], bfr[ni], acc_t[mi][ni], 0, 0, 0);
      __builtin_amdgcn_s_setprio(0);
    }
    // ---- write silu(T) to Tl (per-wave disjoint band); published by next barrier.
    #pragma unroll
    for (int mi = 0; mi < 2; ++mi)
      #pragma unroll
      for (int ni = 0; ni < 4; ++ni)
        #pragma unroll
        for (int jj = 0; jj < 4; ++jj)
          Tl[(wm * 32 + mi * 16 + q * 4 + jj) * 264 + wn * 64 + ni * 16 + r] =
              f2bf(siluf(acc_t[mi][ni][jj]));
    asm volatile("s_waitcnt lgkmcnt(0)" ::: "memory");
    // ---- GEMM2: acc_o += T @ Wout col-block d, tiles g = d*16 + 8..15, A from Tl ----
    #pragma unroll
    for (int i = 0; i < 8; ++i) {
      const int g = d * 16 + 8 + i;
      if (g < 63) asm volatile("s_waitcnt vmcnt(2)" ::: "memory");
      else        asm volatile("s_waitcnt vmcnt(0)" ::: "memory");
      __builtin_amdgcn_s_barrier();
      __builtin_amdgcn_sched_barrier(0);
      if (g + 2 < 64) stageT(g + 2);
      const int slot = g % 3;
      const int kt = i * 32;
      bf16x8 af[2], bfr[4];
      #pragma unroll
      for (int mi = 0; mi < 2; ++mi)
        af[mi] = *(const bf16x8*)&Tl[(wm * 32 + mi * 16 + r) * 264 + kt + q * 8];
      #pragma unroll
      for (int ni = 0; ni < 4; ++ni)
        bfr[ni] = *(const bf16x8*)&Bb[(size_t)slot * 8192 +
                                      ((wn * 64 + ni * 16 + r) * 4 + (q ^ swr)) * 8];
      __builtin_amdgcn_s_setprio(1);
      #pragma unroll
      for (int mi = 0; mi < 2; ++mi)
        #pragma unroll
        for (int ni = 0; ni < 4; ++ni)
          acc_o[mi][ni] = __builtin_amdgcn_mfma_f32_16x16x32_bf16(af[mi], bfr[ni], acc_o[mi][ni], 0, 0, 0);
      __builtin_amdgcn_s_setprio(0);
    }
  }

  // ---- epilogue: fp32 out via two half-row LDS transpose passes (Ttmp aliases Tl) ----
  __syncthreads();                               // all GEMM2 Tl reads consumed
  #pragma unroll
  for (int h = 0; h < 2; ++h) {
    if (wm == h) {
      #pragma unroll
      for (int mi = 0; mi < 2; ++mi)
        #pragma unroll
        for (int ni = 0; ni < 4; ++ni)
          #pragma unroll
          for (int jj = 0; jj < 4; ++jj)
            Ttmp[(mi * 16 + q * 4 + jj) * 260 + wn * 64 + ni * 16 + r] = acc_o[mi][ni][jj];
    }
    __syncthreads();
    #pragma unroll
    for (int pass = 0; pass < 4; ++pass) {
      int id = pass * 512 + tid;                 // 32 rows x 64 float4
      int row = id >> 6, c4 = (id & 63) * 4;
      float4 v = *(const float4*)&Ttmp[row * 260 + c4];
      *(float4*)(out + (long)(r0 + h * 32 + row) * 256 + c4) = v;
    }
    if (h == 0) __syncthreads();                 // stores read before overwrite
  }
}

// ---------------- scan kernels ----------------
struct ScanP {
  const unsigned short* xraw;  // [4][ROWS*256] raw (silu applied here)
  const unsigned short* zraw;
  const unsigned short* bc;    // [4][ROWS*16] raw
  const float* dtv;            // [16][ROWS]  (dir*4+h)
  const float* dA;
  const float* D[4];
};

// phase 1: per-chunk (64 steps) local scan from zero; write end-state S and cum-dA P.
// 512-thread blocks (8 waves = 8 bh slices); CHUNK=64 halves S/carry traffic.
__global__ __launch_bounds__(512) void k_scan1(ScanP sp, float* __restrict__ S,
                                               float* __restrict__ P) {
  __shared__ __align__(16) float Bst[8][CHUNK][8];
  __shared__ float dAs[8][CHUNK];
  const int tid = threadIdx.x;
  const int p = tid & 63;
  const int w = tid >> 6;                       // bh
  const int c = blockIdx.x;
  const int d = blockIdx.y;
  const int bh = w;
  const int b = bh >> 2, h = bh & 3;
  const int rev = d & 1;
  const int t0 = c * CHUNK;
  {
    const int t = t0 + p;                       // p covers 0..63 = full chunk
    const int l = rev ? (L_N - 1 - t) : t;
    const int row = (b << 13) + l;
    uint4 bv = *(const uint4*)(sp.bc + ((long)d * ROWS + row) * 16);
    const unsigned short* bu = (const unsigned short*)&bv;
    float dtvv = sp.dtv[((long)d * 4 + h) * ROWS + row];
    dAs[w][p] = sp.dA[((long)d * 4 + h) * ROWS + row];
    #pragma unroll
    for (int n = 0; n < 8; ++n) Bst[w][p][n] = siluf(bf2f(bu[n])) * dtvv;
  }
  __syncthreads();

  float st[8] = {0, 0, 0, 0, 0, 0, 0, 0};
  float cumdA = 1.f;
  const int l0 = rev ? (L_N - 1 - t0) : t0;
  const unsigned short* xp = sp.xraw + ((long)d * ROWS + (b << 13) + l0) * 256 + h * 64 + p;
  const long stp = rev ? -256L : 256L;

  // double-buffered 4-step load groups
  unsigned short xa[4], xb[4];
  #pragma unroll
  for (int j = 0; j < 4; ++j) xa[j] = xp[(long)j * stp];
  #pragma unroll
  for (int g = 0; g < CHUNK / 4; ++g) {
    if (g < CHUNK / 4 - 1) {
      #pragma unroll
      for (int j = 0; j < 4; ++j) xb[j] = xp[(long)((g + 1) * 4 + j) * stp];
    }
    #pragma unroll
    for (int j = 0; j < 4; ++j) {
      int s = g * 4 + j;
      float x = siluf(bf2f(xa[j]));
      float dA = dAs[w][s];
      f32x4 B0 = *(const f32x4*)&Bst[w][s][0];
      f32x4 B1 = *(const f32x4*)&Bst[w][s][4];
      cumdA *= dA;
      st[0] = fmaf(dA, st[0], x * B0[0]);
      st[1] = fmaf(dA, st[1], x * B0[1]);
      st[2] = fmaf(dA, st[2], x * B0[2]);
      st[3] = fmaf(dA, st[3], x * B0[3]);
      st[4] = fmaf(dA, st[4], x * B1[0]);
      st[5] = fmaf(dA, st[5], x * B1[1]);
      st[6] = fmaf(dA, st[6], x * B1[2]);
      st[7] = fmaf(dA, st[7], x * B1[3]);
    }
    #pragma unroll
    for (int j = 0; j < 4; ++j) xa[j] = xb[j];
  }
  float* Sp = S + ((((long)d * NCHUNK + c) * 8 + bh) * 64 + p) * 8;
  #pragma unroll
  for (int n = 0; n < 8; ++n) Sp[n] = st[n];
  if (p == 0) P[((long)d * NCHUNK + c) * 8 + bh] = cumdA;
}

// phase 2a: group-local combine (16 chunks per group, 256 blocks).
// Writes carry_loc (group-local carry-in per chunk) and group aggregates Sg, Pg.
__global__ __launch_bounds__(512) void k_scan2a(const float* __restrict__ S,
                                                const float* __restrict__ P,
                                                float* __restrict__ carry_loc,
                                                float* __restrict__ Sg,
                                                float* __restrict__ Pg) {
  __shared__ float Pl[GRP];
  const int tid = threadIdx.x;
  const int gid = blockIdx.x;                   // (d*8+bh)*NGRP + g
  const int g = gid & (NGRP - 1);
  const int dbh = gid >> 3;                     // NGRP = 8
  const int d = dbh >> 3, bh = dbh & 7;
  if (tid < GRP) Pl[tid] = P[((long)d * NCHUNK + g * GRP + tid) * 8 + bh];
  __syncthreads();
  float cy = 0.f;
  #pragma unroll
  for (int i = 0; i < GRP; ++i) {
    const int c = g * GRP + i;
    carry_loc[(((long)d * NCHUNK + c) * 8 + bh) * 512 + tid] = cy;
    const float Sv = S[(((long)d * NCHUNK + c) * 8 + bh) * 512 + tid];
    cy = fmaf(Pl[i], cy, Sv);
  }
  Sg[(((long)d * NGRP + g) * 8 + bh) * 512 + tid] = cy;
  if (tid == 0) {
    float pp = 1.f;
    #pragma unroll
    for (int i = 0; i < GRP; ++i) pp *= Pl[i];
    Pg[((long)d * NGRP + g) * 8 + bh] = pp;
  }
}

// phase 2b: sequential combine over the 8 groups -> per-group carry-in (tiny)
__global__ __launch_bounds__(512) void k_scan2b(const float* __restrict__ Sg,
                                                const float* __restrict__ Pg,
                                                float* __restrict__ gcarry) {
  __shared__ float Pgl[NGRP];
  const int tid = threadIdx.x;
  const int dbh = blockIdx.x;                   // 32 blocks
  const int d = dbh >> 3, bh = dbh & 7;
  if (tid < NGRP) Pgl[tid] = Pg[((long)d * NGRP + tid) * 8 + bh];
  __syncthreads();
  float cy = 0.f;
  #pragma unroll
  for (int g = 0; g < NGRP; ++g) {
    gcarry[(((long)d * NGRP + g) * 8 + bh) * 512 + tid] = cy;
    const float Sv = Sg[(((long)d * NGRP + g) * 8 + bh) * 512 + tid];
    cy = fmaf(Pgl[g], cy, Sv);
  }
}

// phase 3: re-scan with carry-in, produce gated y in bf16 (sequential writes).
// Full carry reconstructed on the fly: carry = carry_loc + prefixP(group) * gcarry.
__global__ __launch_bounds__(512) void k_scan3(ScanP sp,
                                               const float* __restrict__ carry_loc,
                                               const float* __restrict__ gcarry,
                                               const float* __restrict__ Pc,
                                               unsigned short* __restrict__ ybf) {
  __shared__ __align__(16) float Bst[8][CHUNK][8];
  __shared__ __align__(16) float Cst[8][CHUNK][8];
  __shared__ float dAs[8][CHUNK];
  __shared__ float Pgr[8][GRP];
  const int tid = threadIdx.x;
  const int p = tid & 63;
  const int w = tid >> 6;                       // bh
  const int c = blockIdx.x;
  const int d = blockIdx.y;
  const int bh = w;
  const int b = bh >> 2, h = bh & 3;
  const int rev = d & 1;
  const float Dv = sp.D[d][h];
  const int t0 = c * CHUNK;
  const int grp = c >> 4, ii = c & 15;
  if (p < ii) Pgr[w][p] = Pc[((long)d * NCHUNK + grp * GRP + p) * 8 + bh];
  {
    const int t = t0 + p;
    const int l = rev ? (L_N - 1 - t) : t;
    const int row = (b << 13) + l;
    const unsigned short* bp = sp.bc + ((long)d * ROWS + row) * 16;
    uint4 bv = *(const uint4*)bp;
    uint4 cv = *(const uint4*)(bp + 8);
    const unsigned short* bu = (const unsigned short*)&bv;
    const unsigned short* cu = (const unsigned short*)&cv;
    float dtvv = sp.dtv[((long)d * 4 + h) * ROWS + row];
    dAs[w][p] = sp.dA[((long)d * 4 + h) * ROWS + row];
    #pragma unroll
    for (int n = 0; n < 8; ++n) Bst[w][p][n] = siluf(bf2f(bu[n])) * dtvv;
    #pragma unroll
    for (int n = 0; n < 8; ++n) Cst[w][p][n] = siluf(bf2f(cu[n]));
  }
  __syncthreads();

  float pref = 1.f;
  for (int k = 0; k < ii; ++k) pref *= Pgr[w][k];
  float st[8];
  {
    const float* clp = carry_loc + ((((long)d * NCHUNK + c) * 8 + bh) * 64 + p) * 8;
    const float* gcp = gcarry + ((((long)d * NGRP + grp) * 8 + bh) * 64 + p) * 8;
    #pragma unroll
    for (int n = 0; n < 8; ++n) st[n] = fmaf(pref, gcp[n], clp[n]);
  }

  const int l0 = rev ? (L_N - 1 - t0) : t0;
  const long base = (long)(b << 13) + l0;
  const unsigned short* xp = sp.xraw + ((long)d * ROWS + base) * 256 + h * 64 + p;
  const unsigned short* zp = sp.zraw + ((long)d * ROWS + base) * 256 + h * 64 + p;
  unsigned short* yp = ybf + ((long)d * ROWS + base) * 256 + h * 64 + p;
  const long stp = rev ? -256L : 256L;

  // double-buffered 4-step load groups (x and z)
  unsigned short xa[4], xb[4], za[4], zb[4];
  #pragma unroll
  for (int j = 0; j < 4; ++j) { xa[j] = xp[(long)j * stp]; za[j] = zp[(long)j * stp]; }
  #pragma unroll
  for (int g = 0; g < CHUNK / 4; ++g) {
    if (g < CHUNK / 4 - 1) {
      #pragma unroll
      for (int j = 0; j < 4; ++j) {
        xb[j] = xp[(long)((g + 1) * 4 + j) * stp];
        zb[j] = zp[(long)((g + 1) * 4 + j) * stp];
      }
    }
    #pragma unroll
    for (int j = 0; j < 4; ++j) {
      int s = g * 4 + j;
      float x = siluf(bf2f(xa[j]));
      float zv = siluf(bf2f(za[j]));
      float dA = dAs[w][s];
      f32x4 B0 = *(const f32x4*)&Bst[w][s][0];
      f32x4 B1 = *(const f32x4*)&Bst[w][s][4];
      f32x4 C0 = *(const f32x4*)&Cst[w][s][0];
      f32x4 C1 = *(const f32x4*)&Cst[w][s][4];
      st[0] = fmaf(dA, st[0], x * B0[0]);
      st[1] = fmaf(dA, st[1], x * B0[1]);
      st[2] = fmaf(dA, st[2], x * B0[2]);
      st[3] = fmaf(dA, st[3], x * B0[3]);
      st[4] = fmaf(dA, st[4], x * B1[0]);
      st[5] = fmaf(dA, st[5], x * B1[1]);
      st[6] = fmaf(dA, st[6], x * B1[2]);
      st[7] = fmaf(dA, st[7], x * B1[3]);
      float y01 = fmaf(st[1], C0[1], st[0] * C0[0]);
      float y23 = fmaf(st[3], C0[3], st[2] * C0[2]);
      float y45 = fmaf(st[5], C1[1], st[4] * C1[0]);
      float y67 = fmaf(st[7], C1[3], st[6] * C1[2]);
      float y = (y01 + y23) + (y45 + y67);
      y = fmaf(Dv, x, y) * zv;
      yp[(long)s * stp] = f2bf(y);
    }
    #pragma unroll
    for (int j = 0; j < 4; ++j) { xa[j] = xb[j]; za[j] = zb[j]; }
  }
}

// ---------------- launch ----------------
extern "C" void kernel_launch(void* const* d_in, const int* in_sizes, int n_in,
                              void* d_out, int out_size, void* d_ws, size_t ws_size,
                              hipStream_t stream) {
  const float* x_H = (const float*)d_in[0];
  const float* x_V = (const float*)d_in[1];
  const float* W_in_H = (const float*)d_in[2];
  const float* W_in_V = (const float*)d_in[3];
  const float* W_out_HF = (const float*)d_in[4];
  const float* W_out_HB = (const float*)d_in[5];
  const float* W_out_VF = (const float*)d_in[6];
  const float* W_out_VB = (const float*)d_in[7];
  const float* W_out = (const float*)d_in[8];
  const float* dt_bias_HF = (const float*)d_in[9];
  const float* A_log_HF = (const float*)d_in[10];
  const float* D_HF = (const float*)d_in[11];
  const float* dt_bias_HB = (const float*)d_in[12];
  const float* A_log_HB = (const float*)d_in[13];
  const float* D_HB = (const float*)d_in[14];
  const float* dt_bias_VF = (const float*)d_in[15];
  const float* A_log_VF = (const float*)d_in[16];
  const float* D_VF = (const float*)d_in[17];
  const float* dt_bias_VB = (const float*)d_in[18];
  const float* A_log_VB = (const float*)d_in[19];
  const float* D_VB = (const float*)d_in[20];
  const int* v2h = (const int*)d_in[21];

  char* ws = (char*)d_ws;
  size_t off = 0;
  auto alloc = [&](size_t bytes) {
    void* pp = ws + off;
    off = (off + bytes + 255) & ~(size_t)255;
    return pp;
  };
  unsigned short* xbf = (unsigned short*)alloc((size_t)2 * ROWS * 256 * 2);      // [2 mats]
  unsigned short* Wt_in = (unsigned short*)alloc((size_t)2 * NPAD * 256 * 2);    // [2 mats]
  unsigned short* Wt_dirs = (unsigned short*)alloc((size_t)4 * 65536 * 2);
  unsigned short* Wt_fin = (unsigned short*)alloc((size_t)256 * 1024 * 2);
  unsigned short* zraw = (unsigned short*)alloc((size_t)4 * ROWS * 256 * 2);
  unsigned short* xraw = (unsigned short*)alloc((size_t)4 * ROWS * 256 * 2);
  unsigned short* bc = (unsigned short*)alloc((size_t)4 * ROWS * 16 * 2);
  float* dtv_arr = (float*)alloc((size_t)16 * ROWS * 4);
  float* dA_arr = (float*)alloc((size_t)16 * ROWS * 4);
  unsigned short* ybf = (unsigned short*)alloc((size_t)4 * ROWS * 256 * 2);
  float* S = (float*)alloc((size_t)4 * NCHUNK * 8 * 512 * 4);
  float* P = (float*)alloc((size_t)4 * NCHUNK * 8 * 4);
  float* carry_loc = (float*)alloc((size_t)4 * NCHUNK * 8 * 512 * 4);
  float* Sg = (float*)alloc((size_t)4 * NGRP * 8 * 512 * 4);
  float* Pg = (float*)alloc((size_t)4 * NGRP * 8 * 4);
  float* gcarry = (float*)alloc((size_t)4 * NGRP * 8 * 512 * 4);
  int* inv = (int*)alloc((size_t)ROWS * 4);

  ScanConsts sc;
  sc.dt_bias[0] = dt_bias_HF; sc.dt_bias[1] = dt_bias_HB;
  sc.dt_bias[2] = dt_bias_VF; sc.dt_bias[3] = dt_bias_VB;
  sc.A_log[0] = A_log_HF; sc.A_log[1] = A_log_HB;
  sc.A_log[2] = A_log_VF; sc.A_log[3] = A_log_VB;
  sc.D[0] = D_HF; sc.D[1] = D_HB; sc.D[2] = D_VF; sc.D[3] = D_VB;

  P4 wdirs;  // cat order: dir0 HF->W_out_HB, dir1 HB->W_out_HF, dir2 VF->W_out_VB, dir3 VB->W_out_VF
  wdirs.p[0] = W_out_HB; wdirs.p[1] = W_out_HF; wdirs.p[2] = W_out_VB; wdirs.p[3] = W_out_VF;

  // merged prep: dtfix (+x cvt) | weights | inv
  k_prep<<<5440, 256, 0, stream>>>(x_H, x_V, W_in_H, W_in_V, wdirs, W_out, v2h, sc,
                                   xbf, dtv_arr, dA_arr, Wt_in, Wt_dirs, Wt_fin, inv);

  EpiIn ep; ep.zraw = zraw; ep.xraw = xraw; ep.bc = bc;

  // input GEMMs (XCD-aware 1D grid, counted-vmcnt ring-3), routing epilogue
  k_gemm_in<<<2304, 256, 0, stream>>>(xbf, Wt_in, ep);

  ScanP sp;
  sp.xraw = xraw; sp.zraw = zraw; sp.bc = bc; sp.dtv = dtv_arr; sp.dA = dA_arr;
  sp.D[0] = D_HF; sp.D[1] = D_HB; sp.D[2] = D_VF; sp.D[3] = D_VB;

  k_scan1<<<dim3(NCHUNK, 4), 512, 0, stream>>>(sp, S, P);
  k_scan2a<<<32 * NGRP, 512, 0, stream>>>(S, P, carry_loc, Sg, Pg);
  k_scan2b<<<32, 512, 0, stream>>>(Sg, Pg, gcarry);
  k_scan3<<<dim3(NCHUNK, 4), 512, 0, stream>>>(sp, carry_loc, gcarry, P, ybf);

  // fused out-proj + final GEMM + 4-dir reduction -> fp32 d_out
  k_fuse<<<256, 512, 0, stream>>>(ybf, Wt_dirs, Wt_fin, inv, (float*)d_out);

  (void)in_sizes; (void)n_in; (void)out_size; (void)ws_size;
}

// Round 13
// 231.924 us; speedup vs baseline: 1.8513x; 1.0246x over previous
//
#include <hip/hip_runtime.h>
#include <hip/hip_bf16.h>

// ---------------- problem constants ----------------
#define B_N 2
#define L_N 8192
#define ROWS 16384                // B_N * L_N
#define CHUNK 64
#define NCHUNK 128                // L_N / CHUNK
#define GRP 16                    // chunks per combine group
#define NGRP 8                    // NCHUNK / GRP
#define NPAD 1152                 // input-proj N padded: 2 x 544 + pad to 9*128

typedef __bf16 bf16x8 __attribute__((ext_vector_type(8)));
typedef float f32x4 __attribute__((ext_vector_type(4)));

// fast silu: 1-ulp rcp instead of IEEE divide
__device__ __forceinline__ float siluf(float v) {
  return v * __builtin_amdgcn_rcpf(1.f + __expf(-v));
}
__device__ __forceinline__ float softplusf_(float v) {
  return fmaxf(v, 0.f) + log1pf(__expf(-fabsf(v)));
}
// native bf16 convert (gfx950 HW cvt, RNE)
__device__ __forceinline__ unsigned short f2bf(float v) {
  union { __bf16 b; unsigned short u; } x;
  x.b = (__bf16)v;
  return x.u;
}
__device__ __forceinline__ float bf2f(unsigned short u) {
  union { unsigned u; float f; } x; x.u = ((unsigned)u) << 16;
  return x.f;
}

// async global->LDS, 16B per lane, LDS dest = wave-uniform base + lane*16
__device__ __forceinline__ void gload_lds16(const unsigned short* g, unsigned short* l) {
  __builtin_amdgcn_global_load_lds(
      (const __attribute__((address_space(1))) unsigned int*)g,
      (__attribute__((address_space(3))) unsigned int*)l, 16, 0, 0);
}

struct P4 { const float* p[4]; };
struct ScanConsts {
  const float* dt_bias[4];
  const float* A_log[4];
  const float* D[4];
};

// ---------------- merged prep + dtfix ----------------
// blocks [0,1024): dtfix (mat = bid>>9, rowblock = bid&511) — exact fp32 dt dot with LDS
//   staging, writes dtv/dA and xbf (bf16 cvt of x).
// blocks [1024,3328): Wt_in; [3328,4352): Wt_dirs; [4352,5376): Wt_fin; [5376,5440): inv
__global__ __launch_bounds__(256) void k_prep(
    const float* __restrict__ xH, const float* __restrict__ xV,
    const float* __restrict__ WH, const float* __restrict__ WV,
    P4 ws, const float* __restrict__ W_out, const int* __restrict__ v2h, ScanConsts sc,
    unsigned short* __restrict__ xbf, float* __restrict__ dtv_arr, float* __restrict__ dA_arr,
    unsigned short* __restrict__ Wt_in, unsigned short* __restrict__ Wt_dirs,
    unsigned short* __restrict__ Wt_fin, int* __restrict__ inv) {
  __shared__ float xs[32][257];
  __shared__ float Wsm[8][260];
  int bid = blockIdx.x;
  int tid = threadIdx.x;
  if (bid < 1024) {
    const int mat = bid >> 9;
    const float* x = mat ? xV : xH;
    const float* W = mat ? WV : WH;
    const int r0 = (bid & 511) * 32;
    for (int i = tid; i < 2048; i += 256) {
      int c = i >> 8, k = i & 255;            // c = sl*4+h
      int sl = c >> 2, h = c & 3;
      Wsm[c][k] = W[(long)k * 1064 + sl * 532 + 528 + h];
    }
    for (int i = tid; i < 32 * 64; i += 256) {
      int rl = i >> 6, kq = (i & 63) * 4;
      float4 v = *(const float4*)(x + (long)(r0 + rl) * 256 + kq);
      xs[rl][kq + 0] = v.x; xs[rl][kq + 1] = v.y; xs[rl][kq + 2] = v.z; xs[rl][kq + 3] = v.w;
    }
    __syncthreads();
    for (int i = tid; i < 32 * 64; i += 256) {
      int rl = i >> 6, kq = (i & 63) * 4;
      ushort4 o;
      o.x = f2bf(xs[rl][kq + 0]);
      o.y = f2bf(xs[rl][kq + 1]);
      o.z = f2bf(xs[rl][kq + 2]);
      o.w = f2bf(xs[rl][kq + 3]);
      *(ushort4*)(xbf + (size_t)mat * ROWS * 256 + (long)(r0 + rl) * 256 + kq) = o;
    }
    const int rl = tid >> 3, c = tid & 7;
    float s = 0.f;
    #pragma unroll 8
    for (int k = 0; k < 256; ++k) s = fmaf(xs[rl][k], Wsm[c][k], s);
    const int sl = c >> 2, h = c & 3;
    const int dir = mat * 2 + sl;
    float dtv = softplusf_(s + sc.dt_bias[dir][h]);
    float dAv = __expf(dtv * (-__expf(sc.A_log[dir][h])));
    long o = ((long)dir * 4 + h) * ROWS + (r0 + rl);
    dtv_arr[o] = dtv;
    dA_arr[o] = dAv;
  } else if (bid < 3328) {
    int i = (bid - 1024) * 256 + tid;         // 2*1152*256
    int z = i / (NPAD * 256);
    int rem = i - z * (NPAD * 256);
    int n = rem >> 8, k = rem & 255;
    const float* W = z ? WV : WH;
    int sl = n >= 544;
    int cc = n - (sl ? 544 : 0);
    float v = (cc < 532) ? W[(long)k * 1064 + sl * 532 + cc] : 0.f;
    Wt_in[i] = f2bf(v);
  } else if (bid < 4352) {
    int i = (bid - 3328) * 256 + tid;         // 4*65536
    int d = i >> 16;
    int rem = i & 65535;
    int n = rem >> 8, k = rem & 255;
    Wt_dirs[i] = f2bf(ws.p[d][(long)k * 256 + n]);
  } else if (bid < 5376) {
    int i = (bid - 4352) * 256 + tid;         // 256*1024, i = n*1024+k
    int n = i >> 10, k = i & 1023;
    Wt_fin[i] = f2bf(W_out[(long)k * 256 + n]);
  } else {
    int m = (bid - 5376) * 256 + tid;
    if (m < ROWS) {
      int b = m >> 13;
      inv[b * L_N + v2h[m]] = m;              // inv[h-row] = v-row
    }
  }
}

// ---------------- bf16 MFMA GEMM (128x128 tile, BK=32, counted-vmcnt ring-3) ----------------
struct EpiIn {
  unsigned short* zraw;   // [4][ROWS*256] raw z (silu applied in scans)
  unsigned short* xraw;   // [4][ROWS*256] raw x
  unsigned short* bc;     // [4][ROWS*16]  raw B|C
};

// input-proj GEMM: ring-3 LDS staging, raw s_barrier + counted s_waitcnt vmcnt(N)
// (never 0 mid-loop): 2 tiles always in flight, no per-phase DMA drain (T4).
// Grid is 1D 2304 with an XCD-aware decode (T1): each XCD owns 16 consecutive A
// row-tiles x all 9 col-tiles x both mats -> A working set (2MB) fits per-XCD L2.
__global__ __launch_bounds__(256) void k_gemm_in(
    const unsigned short* __restrict__ Abase, const unsigned short* __restrict__ Btbase,
    EpiIn ep) {
  __shared__ unsigned short smem[24576];       // 48KB: As[3][4096] | Bs[3][4096]
  const int tid = threadIdx.x;
  const int lane = tid & 63;
  const int wid = tid >> 6;
  const int wm = wid & 1, wn = wid >> 1;
  const int q = lane >> 4, r = lane & 15;
  // XCD-aware decode (bijective: 2304 % 8 == 0)
  const int hbid = blockIdx.x;
  const int xcd = hbid & 7;
  const int j = hbid >> 3;                     // 0..287
  const int m0 = (xcd * 16 + (j & 15)) * 128;  // A row-tile: 16 per XCD
  const int n0 = ((j >> 4) % 9) * 128;
  const int z = j / 144;
  const unsigned short* A = Abase + (long)z * ROWS * 256;
  const unsigned short* Bt = Btbase + (long)z * NPAD * 256;

  // staging descriptors (write-side XOR swizzle matches read-side q^swr)
  int s_row[2], s_ch[2];
  #pragma unroll
  for (int i = 0; i < 2; ++i) {
    int idx = i * 256 + tid;
    s_row[i] = idx >> 2;
    s_ch[i] = (idx & 3) ^ ((s_row[i] >> 1) & 3);
  }

  auto stage = [&](int ti) {
    const int slot = ti % 3;
    const int kt = ti * 32;
    #pragma unroll
    for (int i = 0; i < 2; ++i) {
      gload_lds16(A + (long)(m0 + s_row[i]) * 256 + kt + s_ch[i] * 8,
                  smem + (size_t)slot * 4096 + (size_t)(i * 256 + wid * 64) * 8);
      gload_lds16(Bt + (long)(n0 + s_row[i]) * 256 + kt + s_ch[i] * 8,
                  smem + 12288 + (size_t)slot * 4096 + (size_t)(i * 256 + wid * 64) * 8);
    }
  };

  f32x4 acc[4][4] = {};
  const int swr = (r >> 1) & 3;

  stage(0);
  stage(1);

  #pragma unroll
  for (int i = 0; i < 8; ++i) {
    // wait: all but the NEXT tile's 4 issues done => tile i staged
    if (i < 7) asm volatile("s_waitcnt vmcnt(4)" ::: "memory");
    else       asm volatile("s_waitcnt vmcnt(0)" ::: "memory");
    __builtin_amdgcn_s_barrier();
    __builtin_amdgcn_sched_barrier(0);
    if (i + 2 < 8) stage(i + 2);
    const int slot = i % 3;
    bf16x8 af[4], bfr[4];
    #pragma unroll
    for (int mi = 0; mi < 4; ++mi)
      af[mi] = *(const bf16x8*)&smem[(size_t)slot * 4096 +
                                     ((wm * 64 + mi * 16 + r) * 4 + (q ^ swr)) * 8];
    #pragma unroll
    for (int ni = 0; ni < 4; ++ni)
      bfr[ni] = *(const bf16x8*)&smem[12288 + (size_t)slot * 4096 +
                                      ((wn * 64 + ni * 16 + r) * 4 + (q ^ swr)) * 8];
    __builtin_amdgcn_s_setprio(1);
    #pragma unroll
    for (int mi = 0; mi < 4; ++mi)
      #pragma unroll
      for (int ni = 0; ni < 4; ++ni)
        acc[mi][ni] = __builtin_amdgcn_mfma_f32_16x16x32_bf16(af[mi], bfr[ni], acc[mi][ni], 0, 0, 0);
    __builtin_amdgcn_s_setprio(0);
  }
  __syncthreads();                             // all reads done; staging now dead

  // per-wave transpose region aliases staging: 16 x 72
  unsigned short* tr = smem + wid * (16 * 72);
  #pragma unroll
  for (int mi = 0; mi < 4; ++mi) {
    #pragma unroll
    for (int ni = 0; ni < 4; ++ni)
      #pragma unroll
      for (int j2 = 0; j2 < 4; ++j2)
        tr[(q * 4 + j2) * 72 + ni * 16 + r] = f2bf(acc[mi][ni][j2]);
    asm volatile("s_waitcnt lgkmcnt(0)" ::: "memory");
    #pragma unroll
    for (int pass = 0; pass < 2; ++pass) {
      int rl = pass * 8 + (lane >> 3);
      int c8 = (lane & 7) * 8;
      bf16x8 v = *(const bf16x8*)&tr[rl * 72 + c8];
      int row = m0 + wm * 64 + mi * 16 + rl;
      int col = n0 + wn * 64 + c8;
      int sl = col >= 544;
      int cc = col - (sl ? 544 : 0);
      if (cc < 528) {
        int dir = z * 2 + sl;
        if (cc < 256)
          *(bf16x8*)(ep.zraw + ((long)dir * ROWS + row) * 256 + cc) = v;
        else if (cc < 512)
          *(bf16x8*)(ep.xraw + ((long)dir * ROWS + row) * 256 + cc - 256) = v;
        else
          *(bf16x8*)(ep.bc + ((long)dir * ROWS + row) * 16 + cc - 512) = v;
      }
    }
    asm volatile("s_waitcnt lgkmcnt(0)" ::: "memory");
  }
}

// ---------------- fused out-proj + final GEMM + reduction (ALL 4 dirs) ----------------
// Counted-vmcnt ring-3 pipeline over the GLOBAL 64-tile sequence, now with 1024
// threads / 16 waves (4M x 4N wave tiles of 16x64) -> 16 waves/CU (was 8). Same
// LDS, same tile, same barrier schedule; per-wave MFMA work halves so waits overlap.
// Waves 0-3 stage A (G1 only) + B; waves 4-15 stage B only -> per-wave counted vmcnt.
__global__ __launch_bounds__(1024) void k_fuse(
    const unsigned short* __restrict__ ybf,      // [4][ROWS][256]
    const unsigned short* __restrict__ Wt_dirs,  // [4][256 n][256 k]
    const unsigned short* __restrict__ Wt_fin,   // [256 c][1024 k] (k = d*256+kk)
    const int* __restrict__ inv,
    float* __restrict__ out) {                   // [ROWS*256] fp32
  __shared__ unsigned short smf[47616];          // Ab[3][2048] | Bb[3][8192] | Tl[64*264]
  unsigned short* Ab = smf;                      // 3 x 4KB
  unsigned short* Bb = smf + 6144;               // 3 x 16KB
  unsigned short* Tl = smf + 30720;              // 33.8KB (bf16 T); aliased fp32 in epilogue
  float* Ttmp = (float*)(smf + 30720);           // 32 x 260 fp32 per half-pass (33.3KB)
  const int tid = threadIdx.x;
  const int lane = tid & 63;
  const int wid = tid >> 6;                      // 0..15
  const int wm = wid & 3, wn = wid >> 2;         // 16-row x 64-col wave tiles
  const int q = lane >> 4, r = lane & 15;
  const int r0 = blockIdx.x * 64;
  const int swr = (r >> 1) & 3;
  const bool wA = (wid < 4);                     // waves that stage A in G1 phases

  // A staging (tid<256): row 0..63, chunk swizzled
  const int a_row = tid >> 2;
  const int a_ch = (tid & 3) ^ ((a_row >> 1) & 3);
  const long a_offH = (long)(r0 + a_row) * 256 + a_ch * 8;
  long a_offV = 0;
  if (tid < 256) a_offV = (long)inv[r0 + a_row] * 256 + a_ch * 8;  // v-row gather
  // B staging: single round, 1024 threads cover 256 rows x 4 chunks
  const int b_row = tid >> 2;
  const int b_ch = (tid & 3) ^ ((b_row >> 1) & 3);

  // stage tile g of the 64-tile global sequence into ring slot g%3.
  auto stageT = [&](int g) {
    const int seg = g >> 3, ti = g & 7, kt = ti * 32;
    const int dl = seg >> 1;                     // dir 0..3
    const int slot = g % 3;
    if ((seg & 1) == 0) {                        // G1: A + B(Wt_dirs)
      const long aoff = (dl >= 2) ? a_offV : a_offH;
      if (tid < 256)
        gload_lds16(ybf + (long)dl * ROWS * 256 + aoff + kt,
                    Ab + (size_t)slot * 2048 + (size_t)(wid * 64) * 8);
      gload_lds16(Wt_dirs + (long)dl * 65536 + (long)b_row * 256 + kt + b_ch * 8,
                  Bb + (size_t)slot * 8192 + (size_t)(wid * 64) * 8);
    } else {                                     // G2: B(Wt_fin) only
      gload_lds16(Wt_fin + (long)b_row * 1024 + dl * 256 + kt + b_ch * 8,
                  Bb + (size_t)slot * 8192 + (size_t)(wid * 64) * 8);
    }
  };

  f32x4 acc_o[4] = {};

  stageT(0);
  stageT(1);

  #pragma unroll
  for (int d = 0; d < 4; ++d) {
    // ---- GEMM1: T = y_d[rows,:] @ Wd (K=256), tiles g = d*16 + 0..7 ----
    f32x4 acc_t[4] = {};
    #pragma unroll
    for (int i = 0; i < 8; ++i) {
      const int g = d * 16 + i;
      // wait until tile g staged: outstanding = issues(g+1). g+1 is G1 for i<7
      // (waves 0-3 issued A+B = 2), else G2 (1). Waves 4-15 always 1.
      if (wA) {
        if (i < 7) asm volatile("s_waitcnt vmcnt(2)" ::: "memory");
        else       asm volatile("s_waitcnt vmcnt(1)" ::: "memory");
      } else {
        asm volatile("s_waitcnt vmcnt(1)" ::: "memory");
      }
      __builtin_amdgcn_s_barrier();
      __builtin_amdgcn_sched_barrier(0);
      stageT(g + 2);                             // g+2 <= 57 here
      const int slot = g % 3;
      bf16x8 af, bfr[4];
      af = *(const bf16x8*)&Ab[(size_t)slot * 2048 +
                               ((wm * 16 + r) * 4 + (q ^ swr)) * 8];
      #pragma unroll
      for (int ni = 0; ni < 4; ++ni)
        bfr[ni] = *(const bf16x8*)&Bb[(size_t)slot * 8192 +
                                      ((wn * 64 + ni * 16 + r) * 4 + (q ^ swr)) * 8];
      __builtin_amdgcn_s_setprio(1);
      #pragma unroll
      for (int ni = 0; ni < 4; ++ni)
        acc_t[ni] = __builtin_amdgcn_mfma_f32_16x16x32_bf16(af, bfr[ni], acc_t[ni], 0, 0, 0);
      __builtin_amdgcn_s_setprio(0);
    }
    // ---- write silu(T) to Tl (per-wave disjoint 16x64 band); published by next barrier.
    #pragma unroll
    for (int ni = 0; ni < 4; ++ni)
      #pragma unroll
      for (int jj = 0; jj < 4; ++jj)
        Tl[(wm * 16 + q * 4 + jj) * 264 + wn * 64 + ni * 16 + r] =
            f2bf(siluf(acc_t[ni][jj]));
    asm volatile("s_waitcnt lgkmcnt(0)" ::: "memory");
    // ---- GEMM2: acc_o += T @ Wout col-block d, tiles g = d*16 + 8..15, A from Tl ----
    #pragma unroll
    for (int i = 0; i < 8; ++i) {
      const int g = d * 16 + 8 + i;
      // g+1 is G2 for i<7 (1 issue); at i==7 next is G1 (waves 0-3: 2). Final: 0.
      if (g == 63) {
        asm volatile("s_waitcnt vmcnt(0)" ::: "memory");
      } else if (wA && i == 7) {
        asm volatile("s_waitcnt vmcnt(2)" ::: "memory");
      } else {
        asm volatile("s_waitcnt vmcnt(1)" ::: "memory");
      }
      __builtin_amdgcn_s_barrier();
      __builtin_amdgcn_sched_barrier(0);
      if (g + 2 < 64) stageT(g + 2);
      const int slot = g % 3;
      const int kt = i * 32;
      bf16x8 af, bfr[4];
      af = *(const bf16x8*)&Tl[(wm * 16 + r) * 264 + kt + q * 8];
      #pragma unroll
      for (int ni = 0; ni < 4; ++ni)
        bfr[ni] = *(const bf16x8*)&Bb[(size_t)slot * 8192 +
                                      ((wn * 64 + ni * 16 + r) * 4 + (q ^ swr)) * 8];
      __builtin_amdgcn_s_setprio(1);
      #pragma unroll
      for (int ni = 0; ni < 4; ++ni)
        acc_o[ni] = __builtin_amdgcn_mfma_f32_16x16x32_bf16(af, bfr[ni], acc_o[ni], 0, 0, 0);
      __builtin_amdgcn_s_setprio(0);
    }
  }

  // ---- epilogue: fp32 out via two half-row LDS transpose passes (Ttmp aliases Tl) ----
  __syncthreads();                               // all GEMM2 Tl reads consumed
  #pragma unroll
  for (int h = 0; h < 2; ++h) {
    if ((wm >> 1) == h) {
      #pragma unroll
      for (int ni = 0; ni < 4; ++ni)
        #pragma unroll
        for (int jj = 0; jj < 4; ++jj)
          Ttmp[((wm & 1) * 16 + q * 4 + jj) * 260 + wn * 64 + ni * 16 + r] = acc_o[ni][jj];
    }
    __syncthreads();
    #pragma unroll
    for (int pass = 0; pass < 2; ++pass) {
      int id = pass * 1024 + tid;                // 32 rows x 64 float4
      int row = id >> 6, c4 = (id & 63) * 4;
      float4 v = *(const float4*)&Ttmp[row * 260 + c4];
      *(float4*)(out + (long)(r0 + h * 32 + row) * 256 + c4) = v;
    }
    if (h == 0) __syncthreads();                 // stores read before overwrite
  }
}

// ---------------- scan kernels ----------------
struct ScanP {
  const unsigned short* xraw;  // [4][ROWS*256] raw (silu applied here)
  const unsigned short* zraw;
  const unsigned short* bc;    // [4][ROWS*16] raw
  const float* dtv;            // [16][ROWS]  (dir*4+h)
  const float* dA;
  const float* D[4];
};

// phase 1: per-chunk (64 steps) local scan from zero; write end-state S and cum-dA P.
// 512-thread blocks (8 waves = 8 bh slices); CHUNK=64 halves S/carry traffic.
__global__ __launch_bounds__(512) void k_scan1(ScanP sp, float* __restrict__ S,
                                               float* __restrict__ P) {
  __shared__ __align__(16) float Bst[8][CHUNK][8];
  __shared__ float dAs[8][CHUNK];
  const int tid = threadIdx.x;
  const int p = tid & 63;
  const int w = tid >> 6;                       // bh
  const int c = blockIdx.x;
  const int d = blockIdx.y;
  const int bh = w;
  const int b = bh >> 2, h = bh & 3;
  const int rev = d & 1;
  const int t0 = c * CHUNK;
  {
    const int t = t0 + p;                       // p covers 0..63 = full chunk
    const int l = rev ? (L_N - 1 - t) : t;
    const int row = (b << 13) + l;
    uint4 bv = *(const uint4*)(sp.bc + ((long)d * ROWS + row) * 16);
    const unsigned short* bu = (const unsigned short*)&bv;
    float dtvv = sp.dtv[((long)d * 4 + h) * ROWS + row];
    dAs[w][p] = sp.dA[((long)d * 4 + h) * ROWS + row];
    #pragma unroll
    for (int n = 0; n < 8; ++n) Bst[w][p][n] = siluf(bf2f(bu[n])) * dtvv;
  }
  __syncthreads();

  float st[8] = {0, 0, 0, 0, 0, 0, 0, 0};
  float cumdA = 1.f;
  const int l0 = rev ? (L_N - 1 - t0) : t0;
  const unsigned short* xp = sp.xraw + ((long)d * ROWS + (b << 13) + l0) * 256 + h * 64 + p;
  const long stp = rev ? -256L : 256L;

  // double-buffered 4-step load groups
  unsigned short xa[4], xb[4];
  #pragma unroll
  for (int j = 0; j < 4; ++j) xa[j] = xp[(long)j * stp];
  #pragma unroll
  for (int g = 0; g < CHUNK / 4; ++g) {
    if (g < CHUNK / 4 - 1) {
      #pragma unroll
      for (int j = 0; j < 4; ++j) xb[j] = xp[(long)((g + 1) * 4 + j) * stp];
    }
    #pragma unroll
    for (int j = 0; j < 4; ++j) {
      int s = g * 4 + j;
      float x = siluf(bf2f(xa[j]));
      float dA = dAs[w][s];
      f32x4 B0 = *(const f32x4*)&Bst[w][s][0];
      f32x4 B1 = *(const f32x4*)&Bst[w][s][4];
      cumdA *= dA;
      st[0] = fmaf(dA, st[0], x * B0[0]);
      st[1] = fmaf(dA, st[1], x * B0[1]);
      st[2] = fmaf(dA, st[2], x * B0[2]);
      st[3] = fmaf(dA, st[3], x * B0[3]);
      st[4] = fmaf(dA, st[4], x * B1[0]);
      st[5] = fmaf(dA, st[5], x * B1[1]);
      st[6] = fmaf(dA, st[6], x * B1[2]);
      st[7] = fmaf(dA, st[7], x * B1[3]);
    }
    #pragma unroll
    for (int j = 0; j < 4; ++j) xa[j] = xb[j];
  }
  float* Sp = S + ((((long)d * NCHUNK + c) * 8 + bh) * 64 + p) * 8;
  #pragma unroll
  for (int n = 0; n < 8; ++n) Sp[n] = st[n];
  if (p == 0) P[((long)d * NCHUNK + c) * 8 + bh] = cumdA;
}

// phase 2a: group-local combine (16 chunks per group, 256 blocks).
// Writes carry_loc (group-local carry-in per chunk) and group aggregates Sg, Pg.
__global__ __launch_bounds__(512) void k_scan2a(const float* __restrict__ S,
                                                const float* __restrict__ P,
                                                float* __restrict__ carry_loc,
                                                float* __restrict__ Sg,
                                                float* __restrict__ Pg) {
  __shared__ float Pl[GRP];
  const int tid = threadIdx.x;
  const int gid = blockIdx.x;                   // (d*8+bh)*NGRP + g
  const int g = gid & (NGRP - 1);
  const int dbh = gid >> 3;                     // NGRP = 8
  const int d = dbh >> 3, bh = dbh & 7;
  if (tid < GRP) Pl[tid] = P[((long)d * NCHUNK + g * GRP + tid) * 8 + bh];
  __syncthreads();
  float cy = 0.f;
  #pragma unroll
  for (int i = 0; i < GRP; ++i) {
    const int c = g * GRP + i;
    carry_loc[(((long)d * NCHUNK + c) * 8 + bh) * 512 + tid] = cy;
    const float Sv = S[(((long)d * NCHUNK + c) * 8 + bh) * 512 + tid];
    cy = fmaf(Pl[i], cy, Sv);
  }
  Sg[(((long)d * NGRP + g) * 8 + bh) * 512 + tid] = cy;
  if (tid == 0) {
    float pp = 1.f;
    #pragma unroll
    for (int i = 0; i < GRP; ++i) pp *= Pl[i];
    Pg[((long)d * NGRP + g) * 8 + bh] = pp;
  }
}

// phase 2b: sequential combine over the 8 groups -> per-group carry-in (tiny)
__global__ __launch_bounds__(512) void k_scan2b(const float* __restrict__ Sg,
                                                const float* __restrict__ Pg,
                                                float* __restrict__ gcarry) {
  __shared__ float Pgl[NGRP];
  const int tid = threadIdx.x;
  const int dbh = blockIdx.x;                   // 32 blocks
  const int d = dbh >> 3, bh = dbh & 7;
  if (tid < NGRP) Pgl[tid] = Pg[((long)d * NGRP + tid) * 8 + bh];
  __syncthreads();
  float cy = 0.f;
  #pragma unroll
  for (int g = 0; g < NGRP; ++g) {
    gcarry[(((long)d * NGRP + g) * 8 + bh) * 512 + tid] = cy;
    const float Sv = Sg[(((long)d * NGRP + g) * 8 + bh) * 512 + tid];
    cy = fmaf(Pgl[g], cy, Sv);
  }
}

// phase 3: re-scan with carry-in, produce gated y in bf16 (sequential writes).
// Full carry reconstructed on the fly: carry = carry_loc + prefixP(group) * gcarry.
__global__ __launch_bounds__(512) void k_scan3(ScanP sp,
                                               const float* __restrict__ carry_loc,
                                               const float* __restrict__ gcarry,
                                               const float* __restrict__ Pc,
                                               unsigned short* __restrict__ ybf) {
  __shared__ __align__(16) float Bst[8][CHUNK][8];
  __shared__ __align__(16) float Cst[8][CHUNK][8];
  __shared__ float dAs[8][CHUNK];
  __shared__ float Pgr[8][GRP];
  const int tid = threadIdx.x;
  const int p = tid & 63;
  const int w = tid >> 6;                       // bh
  const int c = blockIdx.x;
  const int d = blockIdx.y;
  const int bh = w;
  const int b = bh >> 2, h = bh & 3;
  const int rev = d & 1;
  const float Dv = sp.D[d][h];
  const int t0 = c * CHUNK;
  const int grp = c >> 4, ii = c & 15;
  if (p < ii) Pgr[w][p] = Pc[((long)d * NCHUNK + grp * GRP + p) * 8 + bh];
  {
    const int t = t0 + p;
    const int l = rev ? (L_N - 1 - t) : t;
    const int row = (b << 13) + l;
    const unsigned short* bp = sp.bc + ((long)d * ROWS + row) * 16;
    uint4 bv = *(const uint4*)bp;
    uint4 cv = *(const uint4*)(bp + 8);
    const unsigned short* bu = (const unsigned short*)&bv;
    const unsigned short* cu = (const unsigned short*)&cv;
    float dtvv = sp.dtv[((long)d * 4 + h) * ROWS + row];
    dAs[w][p] = sp.dA[((long)d * 4 + h) * ROWS + row];
    #pragma unroll
    for (int n = 0; n < 8; ++n) Bst[w][p][n] = siluf(bf2f(bu[n])) * dtvv;
    #pragma unroll
    for (int n = 0; n < 8; ++n) Cst[w][p][n] = siluf(bf2f(cu[n]));
  }
  __syncthreads();

  float pref = 1.f;
  for (int k = 0; k < ii; ++k) pref *= Pgr[w][k];
  float st[8];
  {
    const float* clp = carry_loc + ((((long)d * NCHUNK + c) * 8 + bh) * 64 + p) * 8;
    const float* gcp = gcarry + ((((long)d * NGRP + grp) * 8 + bh) * 64 + p) * 8;
    #pragma unroll
    for (int n = 0; n < 8; ++n) st[n] = fmaf(pref, gcp[n], clp[n]);
  }

  const int l0 = rev ? (L_N - 1 - t0) : t0;
  const long base = (long)(b << 13) + l0;
  const unsigned short* xp = sp.xraw + ((long)d * ROWS + base) * 256 + h * 64 + p;
  const unsigned short* zp = sp.zraw + ((long)d * ROWS + base) * 256 + h * 64 + p;
  unsigned short* yp = ybf + ((long)d * ROWS + base) * 256 + h * 64 + p;
  const long stp = rev ? -256L : 256L;

  // double-buffered 4-step load groups (x and z)
  unsigned short xa[4], xb[4], za[4], zb[4];
  #pragma unroll
  for (int j = 0; j < 4; ++j) { xa[j] = xp[(long)j * stp]; za[j] = zp[(long)j * stp]; }
  #pragma unroll
  for (int g = 0; g < CHUNK / 4; ++g) {
    if (g < CHUNK / 4 - 1) {
      #pragma unroll
      for (int j = 0; j < 4; ++j) {
        xb[j] = xp[(long)((g + 1) * 4 + j) * stp];
        zb[j] = zp[(long)((g + 1) * 4 + j) * stp];
      }
    }
    #pragma unroll
    for (int j = 0; j < 4; ++j) {
      int s = g * 4 + j;
      float x = siluf(bf2f(xa[j]));
      float zv = siluf(bf2f(za[j]));
      float dA = dAs[w][s];
      f32x4 B0 = *(const f32x4*)&Bst[w][s][0];
      f32x4 B1 = *(const f32x4*)&Bst[w][s][4];
      f32x4 C0 = *(const f32x4*)&Cst[w][s][0];
      f32x4 C1 = *(const f32x4*)&Cst[w][s][4];
      st[0] = fmaf(dA, st[0], x * B0[0]);
      st[1] = fmaf(dA, st[1], x * B0[1]);
      st[2] = fmaf(dA, st[2], x * B0[2]);
      st[3] = fmaf(dA, st[3], x * B0[3]);
      st[4] = fmaf(dA, st[4], x * B1[0]);
      st[5] = fmaf(dA, st[5], x * B1[1]);
      st[6] = fmaf(dA, st[6], x * B1[2]);
      st[7] = fmaf(dA, st[7], x * B1[3]);
      float y01 = fmaf(st[1], C0[1], st[0] * C0[0]);
      float y23 = fmaf(st[3], C0[3], st[2] * C0[2]);
      float y45 = fmaf(st[5], C1[1], st[4] * C1[0]);
      float y67 = fmaf(st[7], C1[3], st[6] * C1[2]);
      float y = (y01 + y23) + (y45 + y67);
      y = fmaf(Dv, x, y) * zv;
      yp[(long)s * stp] = f2bf(y);
    }
    #pragma unroll
    for (int j = 0; j < 4; ++j) { xa[j] = xb[j]; za[j] = zb[j]; }
  }
}

// ---------------- launch ----------------
extern "C" void kernel_launch(void* const* d_in, const int* in_sizes, int n_in,
                              void* d_out, int out_size, void* d_ws, size_t ws_size,
                              hipStream_t stream) {
  const float* x_H = (const float*)d_in[0];
  const float* x_V = (const float*)d_in[1];
  const float* W_in_H = (const float*)d_in[2];
  const float* W_in_V = (const float*)d_in[3];
  const float* W_out_HF = (const float*)d_in[4];
  const float* W_out_HB = (const float*)d_in[5];
  const float* W_out_VF = (const float*)d_in[6];
  const float* W_out_VB = (const float*)d_in[7];
  const float* W_out = (const float*)d_in[8];
  const float* dt_bias_HF = (const float*)d_in[9];
  const float* A_log_HF = (const float*)d_in[10];
  const float* D_HF = (const float*)d_in[11];
  const float* dt_bias_HB = (const float*)d_in[12];
  const float* A_log_HB = (const float*)d_in[13];
  const float* D_HB = (const float*)d_in[14];
  const float* dt_bias_VF = (const float*)d_in[15];
  const float* A_log_VF = (const float*)d_in[16];
  const float* D_VF = (const float*)d_in[17];
  const float* dt_bias_VB = (const float*)d_in[18];
  const float* A_log_VB = (const float*)d_in[19];
  const float* D_VB = (const float*)d_in[20];
  const int* v2h = (const int*)d_in[21];

  char* ws = (char*)d_ws;
  size_t off = 0;
  auto alloc = [&](size_t bytes) {
    void* pp = ws + off;
    off = (off + bytes + 255) & ~(size_t)255;
    return pp;
  };
  unsigned short* xbf = (unsigned short*)alloc((size_t)2 * ROWS * 256 * 2);      // [2 mats]
  unsigned short* Wt_in = (unsigned short*)alloc((size_t)2 * NPAD * 256 * 2);    // [2 mats]
  unsigned short* Wt_dirs = (unsigned short*)alloc((size_t)4 * 65536 * 2);
  unsigned short* Wt_fin = (unsigned short*)alloc((size_t)256 * 1024 * 2);
  unsigned short* zraw = (unsigned short*)alloc((size_t)4 * ROWS * 256 * 2);
  unsigned short* xraw = (unsigned short*)alloc((size_t)4 * ROWS * 256 * 2);
  unsigned short* bc = (unsigned short*)alloc((size_t)4 * ROWS * 16 * 2);
  float* dtv_arr = (float*)alloc((size_t)16 * ROWS * 4);
  float* dA_arr = (float*)alloc((size_t)16 * ROWS * 4);
  unsigned short* ybf = (unsigned short*)alloc((size_t)4 * ROWS * 256 * 2);
  float* S = (float*)alloc((size_t)4 * NCHUNK * 8 * 512 * 4);
  float* P = (float*)alloc((size_t)4 * NCHUNK * 8 * 4);
  float* carry_loc = (float*)alloc((size_t)4 * NCHUNK * 8 * 512 * 4);
  float* Sg = (float*)alloc((size_t)4 * NGRP * 8 * 512 * 4);
  float* Pg = (float*)alloc((size_t)4 * NGRP * 8 * 4);
  float* gcarry = (float*)alloc((size_t)4 * NGRP * 8 * 512 * 4);
  int* inv = (int*)alloc((size_t)ROWS * 4);

  ScanConsts sc;
  sc.dt_bias[0] = dt_bias_HF; sc.dt_bias[1] = dt_bias_HB;
  sc.dt_bias[2] = dt_bias_VF; sc.dt_bias[3] = dt_bias_VB;
  sc.A_log[0] = A_log_HF; sc.A_log[1] = A_log_HB;
  sc.A_log[2] = A_log_VF; sc.A_log[3] = A_log_VB;
  sc.D[0] = D_HF; sc.D[1] = D_HB; sc.D[2] = D_VF; sc.D[3] = D_VB;

  P4 wdirs;  // cat order: dir0 HF->W_out_HB, dir1 HB->W_out_HF, dir2 VF->W_out_VB, dir3 VB->W_out_VF
  wdirs.p[0] = W_out_HB; wdirs.p[1] = W_out_HF; wdirs.p[2] = W_out_VB; wdirs.p[3] = W_out_VF;

  // merged prep: dtfix (+x cvt) | weights | inv
  k_prep<<<5440, 256, 0, stream>>>(x_H, x_V, W_in_H, W_in_V, wdirs, W_out, v2h, sc,
                                   xbf, dtv_arr, dA_arr, Wt_in, Wt_dirs, Wt_fin, inv);

  EpiIn ep; ep.zraw = zraw; ep.xraw = xraw; ep.bc = bc;

  // input GEMMs (XCD-aware 1D grid, counted-vmcnt ring-3), routing epilogue
  k_gemm_in<<<2304, 256, 0, stream>>>(xbf, Wt_in, ep);

  ScanP sp;
  sp.xraw = xraw; sp.zraw = zraw; sp.bc = bc; sp.dtv = dtv_arr; sp.dA = dA_arr;
  sp.D[0] = D_HF; sp.D[1] = D_HB; sp.D[2] = D_VF; sp.D[3] = D_VB;

  k_scan1<<<dim3(NCHUNK, 4), 512, 0, stream>>>(sp, S, P);
  k_scan2a<<<32 * NGRP, 512, 0, stream>>>(S, P, carry_loc, Sg, Pg);
  k_scan2b<<<32, 512, 0, stream>>>(Sg, Pg, gcarry);
  k_scan3<<<dim3(NCHUNK, 4), 512, 0, stream>>>(sp, carry_loc, gcarry, P, ybf);

  // fused out-proj + final GEMM + 4-dir reduction -> fp32 d_out (1024 thr, 16 waves)
  k_fuse<<<256, 1024, 0, stream>>>(ybf, Wt_dirs, Wt_fin, inv, (float*)d_out);

  (void)in_sizes; (void)n_in; (void)out_size; (void)ws_size;
}